// Round 9
// baseline (1021.606 us; speedup 1.0000x reference)
//
#include <hip/hip_runtime.h>
#include <hip/hip_bf16.h>

// Problem constants (B,T,NI,NH,NO fixed by the reference)
constexpr int kB  = 64;
constexpr int kT  = 100;
constexpr int kNI = 700;
constexpr int kNH = 512;
constexpr int kNO = 20;
constexpr float TAU   = 0.6f;
constexpr float TAU_O = 0.6f;
constexpr float THR   = 0.6f;
constexpr float LR    = 0.05f;

constexpr size_t BNH = (size_t)kB * kNH;   // 32768
constexpr size_t BNI = (size_t)kB * kNI;   // 44800
constexpr size_t BNO = (size_t)kB * kNO;   // 1280
constexpr int kK   = kT * kB;              // 6400 (grad-GEMM K; b-major: k = b*100+t)
constexpr int kKP  = 704;                  // padded K for xw GEMM

typedef __attribute__((ext_vector_type(8))) short short8;
typedef __attribute__((ext_vector_type(4))) float f32x4;

// ---------------- workspace layout (float offsets) ---------------------------
constexpr size_t O_XW   = 0;                                // [T, t*64+b, NH] 3,276,800
constexpr size_t O_PGF  = 0;                                // 4 x [512][768] = 1,572,864
constexpr size_t O_PGR  = 1572864;                          // 4 x [512][512] = 1,048,576
constexpr size_t O_PGO  = 2621440;                          // 8 x [20][512]  = 81,920
constexpr size_t O_HSUR = 3276800;                          // [T,B,NH] 3,276,800
constexpr size_t O_TIB  = 3276800;                          // bf16 [700][6400] (overlays HSUR post-fwd)
constexpr size_t O_TIN  = 6553600;                          // [T,B,NI] 4,480,000
constexpr size_t O_HS   = 11033600;                         // [T+1,B,NH] (row t = hs_{t-1})
constexpr size_t O_ERR  = 14343168;                         // [T,B,NO] errf 128,000
constexpr size_t O_WT   = 14471168;                         // [704,512] 360,448
constexpr size_t O_MTB  = 14831616;                         // bf16 [512][6400]
constexpr size_t O_TRB  = 16470016;                         // bf16 [512][6400]
constexpr size_t O_MSK  = 18108416;                         // u64 [T][B][8]
constexpr size_t WS_FLOATS = 18210816;                      // ~72.8 MB

// d_out layout
constexpr size_t OUT_GF = (size_t)kB * kT * kNO;
constexpr size_t OUT_GR = OUT_GF + (size_t)kNH * kNI;
constexpr size_t OUT_GO = OUT_GR + (size_t)kNH * kNH;

// ---- merged prep: blocks 0..351 transpose w_fc1 -> wT; blocks 352.. tin scan
__global__ __launch_bounds__(256) void k_prep(const float* __restrict__ w,
                                              const float* __restrict__ x,
                                              float* __restrict__ wT,
                                              float* __restrict__ tin) {
    int bx = blockIdx.x, tid = threadIdx.x;
    if (bx < 352) {
        __shared__ float tile[32][33];
        int i0 = (bx % 22) * 32, r0 = (bx / 22) * 32;
        int tx = tid & 31, ty = tid >> 5;  // 32 x 8
        #pragma unroll
        for (int k = 0; k < 32; k += 8) {
            int i = i0 + tx;
            tile[ty + k][tx] = (i < kNI) ? w[(size_t)(r0 + ty + k) * kNI + i] : 0.f;
        }
        __syncthreads();
        #pragma unroll
        for (int k = 0; k < 32; k += 8) {
            int i = i0 + ty + k;
            wT[(size_t)i * kNH + r0 + tx] = tile[tx][ty + k];
        }
    } else {
        int idx = (bx - 352) * 256 + tid;   // < B*NI
        int b = idx / kNI, i = idx % kNI;
        const float* xp = x + (size_t)b * kT * kNI + i;
        float v = 0.f;
        for (int t = 0; t < kT; t++) {
            v = TAU * v + xp[(size_t)t * kNI];
            tin[(size_t)t * BNI + idx] = v;
        }
    }
}

// ---- XW = Xperm @ wT : C[m=t*64+b, n<512], K=704 (fp32, exact) --------------
__global__ __launch_bounds__(256) void k_xw2(const float* __restrict__ x,
                                             const float* __restrict__ wT,
                                             float* __restrict__ XW) {
    int bx = blockIdx.x;
    int mt = bx % 50, nt = bx / 50;
    int m0 = mt * 128, n0 = nt * 128;
    int tid = threadIdx.x, tx = tid & 15, ty = tid >> 4;
    __shared__ float As[128][20];
    __shared__ float Bs[16][128];
    float acc[8][8] = {};
    int arow = tid >> 1, ahalf = tid & 1;
    int bb = (m0 + arow) & 63, tt = (m0 + arow) >> 6;
    const float* ap = x + ((size_t)bb * kT + tt) * kNI;
    for (int k0 = 0; k0 < kKP; k0 += 16) {
        #pragma unroll
        for (int u = 0; u < 2; u++) {
            int k = k0 + ahalf * 8 + u * 4;
            float4 v = (k + 3 < kNI) ? *(const float4*)(ap + k)
                                     : make_float4(0.f, 0.f, 0.f, 0.f);
            *(float4*)&As[arow][ahalf * 8 + u * 4] = v;
        }
        #pragma unroll
        for (int u = 0; u < 2; u++) {
            int f = tid * 2 + u;
            int kk = f >> 5, c4 = f & 31;
            *(float4*)&Bs[kk][c4 * 4] =
                *(const float4*)(wT + (size_t)(k0 + kk) * kNH + n0 + c4 * 4);
        }
        __syncthreads();
        #pragma unroll
        for (int kk = 0; kk < 16; kk++) {
            float av[8];
            #pragma unroll
            for (int i = 0; i < 4; i++) {
                av[i]     = As[ty * 4 + i][kk];
                av[4 + i] = As[64 + ty * 4 + i][kk];
            }
            float4 b0 = *(const float4*)&Bs[kk][tx * 4];
            float4 b1 = *(const float4*)&Bs[kk][64 + tx * 4];
            float bvv[8] = {b0.x, b0.y, b0.z, b0.w, b1.x, b1.y, b1.z, b1.w};
            #pragma unroll
            for (int i = 0; i < 8; i++)
                #pragma unroll
                for (int j = 0; j < 8; j++) acc[i][j] += av[i] * bvv[j];
        }
        __syncthreads();
    }
    #pragma unroll
    for (int i = 0; i < 8; i++) {
        int m = m0 + ((i < 4) ? (ty * 4 + i) : (64 + ty * 4 + i - 4));
        float* dst = XW + (size_t)m * kNH + n0;
        *(float4*)(dst + tx * 4)      = make_float4(acc[i][0], acc[i][1], acc[i][2], acc[i][3]);
        *(float4*)(dst + 64 + tx * 4) = make_float4(acc[i][4], acc[i][5], acc[i][6], acc[i][7]);
    }
}

// ---- fused forward: ONE block of 832 threads per sample, ONE barrier/step ---
// Column-sliced gather: wave w (0..7) owns neuron columns [64w,64w+64); walks
// ALL 8 spike words with 8-deep batched dword loads (8 accumulators) so 8
// loads are in flight per wave. Each wave updates its own neurons and ballots
// its own mask word -> no partial[] reduction, no second barrier.
// Waves 8-12: output LIF layer one step behind (reads mh[t-1]).
// Tail: errf reverse-scan in LDS + mtb (bf16, b-major k) production.
__global__ __launch_bounds__(832) void k_forward(float* __restrict__ ws,
                                                 const float* __restrict__ label,
                                                 const float* __restrict__ w_rec,
                                                 const float* __restrict__ w_out,
                                                 float* __restrict__ dout,
                                                 unsigned long long* __restrict__ gmask) {
    __shared__ float wout_ld[kNO * kNH];          // 40 KB
    __shared__ unsigned long long mh[kT * 8];     // 6.4 KB mask history
    __shared__ float errh[kT * kNO];              // 8 KB err/errf history

    int b = blockIdx.x, tid = threadIdx.x;
    int wave = tid >> 6, lane = tid & 63;
    for (int e = tid; e < kNO * kNH; e += 832) wout_ld[e] = w_out[e];
    float hm = 0.f, sp_prev = 0.f;
    float om_r[4] = {0.f, 0.f, 0.f, 0.f}, os_r[4] = {0.f, 0.f, 0.f, 0.f};
    int q = wave - 8;
    const float* wrp = w_rec + (wave << 6) + lane;   // column slice base
    __syncthreads();

    for (int t = 0; t < kT; t++) {
        if (wave < 8) {
            float xw = ws[O_XW + ((size_t)t * 64 + b) * kNH + tid];  // prefetch
            float a0 = 0.f, a1 = 0.f, a2 = 0.f, a3 = 0.f;
            float a4 = 0.f, a5 = 0.f, a6 = 0.f, a7 = 0.f;
            if (t > 0) {
                #pragma unroll
                for (int k = 0; k < 8; k++) {
                    unsigned long long m = mh[(t - 1) * 8 + k];
                    const float* base = wrp + (size_t)(k << 6) * kNH;
                    int g8 = __popcll(m) >> 3;
                    for (int g = 0; g < g8; g++) {
                        int j0 = __builtin_ctzll(m); m &= m - 1;
                        int j1 = __builtin_ctzll(m); m &= m - 1;
                        int j2 = __builtin_ctzll(m); m &= m - 1;
                        int j3 = __builtin_ctzll(m); m &= m - 1;
                        int j4 = __builtin_ctzll(m); m &= m - 1;
                        int j5 = __builtin_ctzll(m); m &= m - 1;
                        int j6 = __builtin_ctzll(m); m &= m - 1;
                        int j7 = __builtin_ctzll(m); m &= m - 1;
                        float v0 = base[(size_t)j0 * kNH];
                        float v1 = base[(size_t)j1 * kNH];
                        float v2 = base[(size_t)j2 * kNH];
                        float v3 = base[(size_t)j3 * kNH];
                        float v4 = base[(size_t)j4 * kNH];
                        float v5 = base[(size_t)j5 * kNH];
                        float v6 = base[(size_t)j6 * kNH];
                        float v7 = base[(size_t)j7 * kNH];
                        a0 += v0; a1 += v1; a2 += v2; a3 += v3;
                        a4 += v4; a5 += v5; a6 += v6; a7 += v7;
                    }
                    while (m) {
                        int j = __builtin_ctzll(m); m &= m - 1;
                        a0 += base[(size_t)j * kNH];
                    }
                }
            }
            float rec = ((a0 + a1) + (a2 + a3)) + ((a4 + a5) + (a6 + a7));
            hm = TAU * hm * (1.f - sp_prev) + (xw + rec);
            bool v = (hm >= THR);
            float sp = v ? 1.f : 0.f;
            sp_prev = sp;
            ws[O_HSUR + (size_t)t * BNH + (size_t)b * kNH + tid] =
                TAU * fmaxf(0.f, 1.f - fabsf(hm - THR) * (1.f / THR));
            unsigned long long bal = __ballot(v);   // this wave = mask word `wave`
            if (lane == 0) {
                mh[t * 8 + wave] = bal;
                gmask[((size_t)t * 64 + b) * 8 + wave] = bal;
            }
        } else if (t > 0) {
            // output LIF layer for step t-1 (wave q = 0..4)
            int to = t - 1;
            unsigned long long mk[8];
            #pragma unroll
            for (int k = 0; k < 8; k++) mk[k] = mh[to * 8 + k];
            #pragma unroll
            for (int r = 0; r < 4; r++) {
                int o = q * 4 + r;
                float p = 0.f;
                #pragma unroll
                for (int k = 0; k < 8; k++)
                    if ((mk[k] >> lane) & 1) p += wout_ld[o * kNH + 64 * k + lane];
                #pragma unroll
                for (int off = 32; off >= 1; off >>= 1) p += __shfl_xor(p, off);
                if (lane == 0) {
                    float om_n = TAU * om_r[r] * (1.f - os_r[r]) + p;
                    float os_n = (om_n >= THR) ? 1.f : 0.f;
                    om_r[r] = om_n; os_r[r] = os_n;
                    errh[to * kNO + o] = os_n - label[((size_t)b * kT + to) * kNO + o];
                    dout[((size_t)b * kT + to) * kNO + o] = os_n;
                }
            }
        }
        __syncthreads();   // single barrier: publishes mh[t] for step t+1
    }
    // ---- tail 1: output layer for t = 99 ----
    if (wave >= 8) {
        int to = kT - 1;
        unsigned long long mk[8];
        #pragma unroll
        for (int k = 0; k < 8; k++) mk[k] = mh[to * 8 + k];
        #pragma unroll
        for (int r = 0; r < 4; r++) {
            int o = q * 4 + r;
            float p = 0.f;
            #pragma unroll
            for (int k = 0; k < 8; k++)
                if ((mk[k] >> lane) & 1) p += wout_ld[o * kNH + 64 * k + lane];
            #pragma unroll
            for (int off = 32; off >= 1; off >>= 1) p += __shfl_xor(p, off);
            if (lane == 0) {
                float om_n = TAU * om_r[r] * (1.f - os_r[r]) + p;
                float os_n = (om_n >= THR) ? 1.f : 0.f;
                errh[to * kNO + o] = os_n - label[((size_t)b * kT + to) * kNO + o];
                dout[((size_t)b * kT + to) * kNO + o] = os_n;
            }
        }
    }
    __syncthreads();
    // ---- tail 2: reverse kappa scan (LDS) + errf -> global (t-major, for go) -
    if (wave == 8 && lane < kNO) {
        float v = 0.f;
        for (int t = kT - 1; t >= 0; t--) {
            v = errh[t * kNO + lane] + TAU_O * v;
            errh[t * kNO + lane] = v;
            ws[O_ERR + (size_t)t * BNO + (size_t)b * kNO + lane] = v;
        }
    }
    __syncthreads();
    // ---- tail 3: mtb[r][b*100+t] = bf16(LR*(errf@w_out)[r]*hsur[t][b][r]) ----
    if (tid < kNH) {
        float wreg[kNO];
        #pragma unroll
        for (int o = 0; o < kNO; o++) wreg[o] = wout_ld[o * kNH + tid];
        unsigned short* mtb = (unsigned short*)(ws + O_MTB);
        size_t rowoff = (size_t)tid * kK + (size_t)b * 100;
        for (int tq = 0; tq < 25; tq++) {
            unsigned long long w8 = 0;
            #pragma unroll
            for (int u = 0; u < 4; u++) {
                int t = tq * 4 + u;
                float s = 0.f;
                #pragma unroll
                for (int o = 0; o < kNO; o++) s += errh[t * kNO + o] * wreg[o];
                float val = LR * s * ws[O_HSUR + (size_t)t * BNH + (size_t)b * kNH + tid];
                __hip_bfloat16 bv = __float2bfloat16(val);
                w8 |= ((unsigned long long)*(unsigned short*)&bv) << (16 * u);
            }
            *(unsigned long long*)&mtb[rowoff + tq * 4] = w8;
        }
    }
}

// ---- merged post: blocks 0..127 densify hs + trb (b-major); rest castT(tin) -
__global__ __launch_bounds__(256) void k_post_cast(float* __restrict__ ws,
                                                   const unsigned long long* __restrict__ gmask) {
    int bx = blockIdx.x, tid = threadIdx.x;
    if (bx < 128) {
        size_t idx = (size_t)bx * 256 + tid;  // < BNH
        {   // dense hs[t+1][b][n] (t-major, for go GEMM)
            int b = (int)(idx >> 9), n = (int)(idx & 511);
            int w = n >> 6, bit = n & 63;
            for (int t = 0; t < kT; t++) {
                float cur = (float)((gmask[((size_t)t * 64 + b) * 8 + w] >> bit) & 1ull);
                ws[O_HS + (size_t)(t + 1) * BNH + idx] = cur;
            }
        }
        {   // trb[n][b*100+t] = bf16(trec), b-major k
            int n = (int)(idx >> 6), b = (int)(idx & 63);
            int w = n >> 6, bit = n & 63;
            __hip_bfloat16* trb = (__hip_bfloat16*)(ws + O_TRB);
            size_t rowoff = (size_t)n * kK + (size_t)b * 100;
            float v = 0.f, p = 0.f;
            for (int t = 0; t < kT; t++) {
                v = TAU * v + p;
                trb[rowoff + t] = __float2bfloat16(v);
                p = (float)((gmask[((size_t)t * 64 + b) * 8 + w] >> bit) & 1ull);
            }
        }
    } else {
        // castT: tib[n][b*100+t] = bf16(tin[t][b][n]), n < 700
        __shared__ float tile[32][33];
        int v = bx - 128;                    // 0..4399 (200 x 22)
        int k0 = (v % 200) * 32, n0 = (v / 200) * 32;
        int tx = tid & 31, ty = tid >> 5;    // 32 x 8
        const float* src = ws + O_TIN;
        __hip_bfloat16* dst = (__hip_bfloat16*)(ws + O_TIB);
        #pragma unroll
        for (int j = 0; j < 32; j += 8) {
            int kk = k0 + ty + j;            // b-major k
            int bb = kk / 100, tt = kk - bb * 100;
            int n = n0 + tx;
            tile[ty + j][tx] = (n < kNI) ? src[(size_t)tt * BNI + (size_t)bb * kNI + n] : 0.f;
        }
        __syncthreads();
        #pragma unroll
        for (int j = 0; j < 32; j += 8) {
            int n = n0 + ty + j;
            if (n < kNI) dst[(size_t)n * kK + k0 + tx] = __float2bfloat16(tile[tx][ty + j]);
        }
    }
}

// ---- bf16 MFMA NT GEMM: C[m,n] = sum_k A[m][k]*B[n][k], K=6400, splitK=4 ----
__global__ __launch_bounds__(256) void k_gemm_nt(const unsigned short* __restrict__ A,
                                                 const unsigned short* __restrict__ B,
                                                 float* __restrict__ Cpart,
                                                 int Nrows, int ldc) {
    constexpr int KC = kK / 4, BK = 64, LDT = 72;
    int bx = blockIdx.x;
    int s = bx & 3, mt = (bx >> 2) & 3, nt = bx >> 4;
    int m0 = mt * 128, n0 = nt * 128, k0 = s * KC;
    int tid = threadIdx.x;
    int wave = tid >> 6, lane = tid & 63;
    int wm = wave & 1, wn = wave >> 1;
    __shared__ unsigned short As[128 * LDT];
    __shared__ unsigned short Bs[128 * LDT];
    f32x4 acc[4][4];
    #pragma unroll
    for (int i = 0; i < 4; i++)
        #pragma unroll
        for (int j = 0; j < 4; j++) acc[i][j] = (f32x4){0.f, 0.f, 0.f, 0.f};

    for (int kb = 0; kb < KC; kb += BK) {
        int kg = k0 + kb;
        #pragma unroll
        for (int p = 0; p < 4; p++) {
            int f = tid + p * 256;
            int row = f >> 3, seg = f & 7;
            *(short8*)&As[row * LDT + seg * 8] =
                *(const short8*)&A[(size_t)(m0 + row) * kK + kg + seg * 8];
            short8 bv = {};
            if (n0 + row < Nrows)
                bv = *(const short8*)&B[(size_t)(n0 + row) * kK + kg + seg * 8];
            *(short8*)&Bs[row * LDT + seg * 8] = bv;
        }
        __syncthreads();
        #pragma unroll
        for (int h = 0; h < 2; h++) {
            int kof = h * 32 + (lane >> 4) * 8;
            short8 af[4], bf[4];
            #pragma unroll
            for (int i = 0; i < 4; i++)
                af[i] = *(short8*)&As[(wm * 64 + i * 16 + (lane & 15)) * LDT + kof];
            #pragma unroll
            for (int j = 0; j < 4; j++)
                bf[j] = *(short8*)&Bs[(wn * 64 + j * 16 + (lane & 15)) * LDT + kof];
            #pragma unroll
            for (int i = 0; i < 4; i++)
                #pragma unroll
                for (int j = 0; j < 4; j++)
                    acc[i][j] = __builtin_amdgcn_mfma_f32_16x16x32_bf16(af[i], bf[j], acc[i][j], 0, 0, 0);
        }
        __syncthreads();
    }
    float* C = Cpart + (size_t)s * kNH * ldc;
    int rbase = (lane >> 4) * 4, col = lane & 15;
    #pragma unroll
    for (int i = 0; i < 4; i++)
        #pragma unroll
        for (int j = 0; j < 4; j++) {
            int n = n0 + wn * 64 + j * 16 + col;
            #pragma unroll
            for (int r = 0; r < 4; r++) {
                int m = m0 + wm * 64 + i * 16 + rbase + r;
                C[(size_t)m * ldc + n] = acc[i][j][r];
            }
        }
}

// ---- small TN GEMM for go (M=20), fp32, t-major k ---------------------------
__global__ __launch_bounds__(256) void k_gemmTN_go(const float* __restrict__ A,
                                                   const float* __restrict__ Bm,
                                                   float* __restrict__ Cpart) {
    int bx = blockIdx.x, tid = threadIdx.x;  // grid 64 = 8 s * 8 nt
    int s = bx & 7, nt = bx >> 3;
    int n0 = nt * 64, k0 = s * 800;
    __shared__ float As[16][64];
    __shared__ float Bs[16][64];
    int tx = tid & 15, ty = tid >> 4;
    float acc[4][4] = {};
    for (int kb = 0; kb < 800; kb += 16) {
        #pragma unroll
        for (int e = tid; e < 1024; e += 256) {
            int kk = e >> 6, c = e & 63;
            size_t gk = (size_t)(k0 + kb + kk);
            As[kk][c] = (c < kNO) ? A[gk * kNO + c] : 0.f;
            Bs[kk][c] = Bm[gk * kNH + n0 + c];
        }
        __syncthreads();
        #pragma unroll
        for (int kk = 0; kk < 16; kk++) {
            float4 av = *(const float4*)&As[kk][ty * 4];
            float4 bv = *(const float4*)&Bs[kk][tx * 4];
            float aa[4] = {av.x, av.y, av.z, av.w};
            float bb[4] = {bv.x, bv.y, bv.z, bv.w};
            #pragma unroll
            for (int a = 0; a < 4; a++)
                #pragma unroll
                for (int c = 0; c < 4; c++) acc[a][c] += aa[a] * bb[c];
        }
        __syncthreads();
    }
    float* Cs = Cpart + (size_t)s * kNO * kNH;
    #pragma unroll
    for (int a = 0; a < 4; a++) {
        int m = ty * 4 + a;
        if (m >= kNO) continue;
        #pragma unroll
        for (int c = 0; c < 4; c++)
            Cs[(size_t)m * kNH + n0 + tx * 4 + c] = acc[a][c];
    }
}

// ---- merged reduction: gf (4 slices), gr (4 slices), go (8 slices) ----------
__global__ void k_reduce_all(const float* __restrict__ ws, float* __restrict__ dout) {
    int idx = blockIdx.x * 256 + threadIdx.x;  // < 630784
    const int NGF = kNH * kNI, NGR = kNH * kNH, NGO = kNO * kNH;
    float s = 0.f;
    if (idx < NGF) {
        int m = idx / kNI, n = idx - m * kNI;
        size_t src = O_PGF + (size_t)m * 768 + n;
        #pragma unroll
        for (int k = 0; k < 4; k++) s += ws[src + (size_t)k * kNH * 768];
        dout[OUT_GF + idx] = s;   // LR folded into mtb
    } else if (idx < NGF + NGR) {
        int j = idx - NGF;
        #pragma unroll
        for (int k = 0; k < 4; k++) s += ws[O_PGR + j + (size_t)k * NGR];
        dout[OUT_GR + j] = s;
    } else if (idx < NGF + NGR + NGO) {
        int j = idx - NGF - NGR;
        #pragma unroll
        for (int k = 0; k < 8; k++) s += ws[O_PGO + (size_t)k * NGO + j];
        dout[OUT_GO + j] = LR * s;
    }
}

extern "C" void kernel_launch(void* const* d_in, const int* in_sizes, int n_in,
                              void* d_out, int out_size, void* d_ws, size_t ws_size,
                              hipStream_t stream) {
    (void)in_sizes; (void)n_in; (void)out_size;
    const float* x     = (const float*)d_in[0];
    const float* label = (const float*)d_in[1];
    const float* w_fc1 = (const float*)d_in[3];
    const float* w_rec = (const float*)d_in[4];
    const float* w_out = (const float*)d_in[5];
    float* out = (float*)d_out;
    float* ws  = (float*)d_ws;

    if (ws_size < WS_FLOATS * sizeof(float)) return;

    __hip_bfloat16* mtb = (__hip_bfloat16*)(ws + O_MTB);
    __hip_bfloat16* trb = (__hip_bfloat16*)(ws + O_TRB);
    __hip_bfloat16* tib = (__hip_bfloat16*)(ws + O_TIB);
    unsigned long long* gmask = (unsigned long long*)(ws + O_MSK);

    k_prep<<<527, 256, 0, stream>>>(w_fc1, x, ws + O_WT, ws + O_TIN);
    k_xw2<<<200, 256, 0, stream>>>(x, ws + O_WT, ws + O_XW);

    k_forward<<<kB, 832, 0, stream>>>(ws, label, w_rec, w_out, out, gmask);

    k_post_cast<<<4528, 256, 0, stream>>>(ws, gmask);   // hs + trb + tib

    k_gemm_nt<<<96, 256, 0, stream>>>((const unsigned short*)mtb, (const unsigned short*)tib,
                                      ws + O_PGF, kNI, 768);
    k_gemm_nt<<<64, 256, 0, stream>>>((const unsigned short*)mtb, (const unsigned short*)trb,
                                      ws + O_PGR, kNH, kNH);
    k_gemmTN_go<<<64, 256, 0, stream>>>(ws + O_ERR, ws + O_HS + BNH, ws + O_PGO);

    k_reduce_all<<<2464, 256, 0, stream>>>(ws, out);
}

// Round 10
// 659.113 us; speedup vs baseline: 1.5500x; 1.5500x over previous
//
#include <hip/hip_runtime.h>
#include <hip/hip_bf16.h>

// Problem constants (B,T,NI,NH,NO fixed by the reference)
constexpr int kB  = 64;
constexpr int kT  = 100;
constexpr int kNI = 700;
constexpr int kNH = 512;
constexpr int kNO = 20;
constexpr float TAU   = 0.6f;
constexpr float TAU_O = 0.6f;
constexpr float THR   = 0.6f;
constexpr float LR    = 0.05f;

constexpr size_t BNH = (size_t)kB * kNH;   // 32768
constexpr size_t BNI = (size_t)kB * kNI;   // 44800
constexpr size_t BNO = (size_t)kB * kNO;   // 1280
constexpr int kK   = kT * kB;              // 6400 (grad-GEMM K; b-major: k = b*100+t)
constexpr int kKP  = 704;                  // padded K for xw GEMM

typedef __attribute__((ext_vector_type(8))) short short8;
typedef __attribute__((ext_vector_type(4))) float f32x4;

// ---------------- workspace layout (float offsets) ---------------------------
constexpr size_t O_XW   = 0;                                // [T, t*64+b, NH]
constexpr size_t O_PGF  = 0;                                // 4 x [512][768]
constexpr size_t O_PGR  = 1572864;                          // 4 x [512][512]
constexpr size_t O_PGO  = 2621440;                          // 8 x [20][512]
constexpr size_t O_HSUR = 3276800;                          // [T,B,NH]
constexpr size_t O_TIB  = 3276800;                          // bf16 [700][6400] (overlays HSUR post-fwd)
constexpr size_t O_TIN  = 6553600;                          // [T,B,NI]
constexpr size_t O_HS   = 11033600;                         // [T+1,B,NH] (row t = hs_{t-1})
constexpr size_t O_ERR  = 14343168;                         // [T,B,NO] errf
constexpr size_t O_WT   = 14471168;                         // [704,512]
constexpr size_t O_MTB  = 14831616;                         // bf16 [512][6400], b-major k
constexpr size_t O_TRB  = 16470016;                         // bf16 [512][6400], b-major k
constexpr size_t O_MSK  = 18108416;                         // u64 [T][B][8]
constexpr size_t WS_FLOATS = 18210816;                      // ~72.8 MB

// d_out layout
constexpr size_t OUT_GF = (size_t)kB * kT * kNO;
constexpr size_t OUT_GR = OUT_GF + (size_t)kNH * kNI;
constexpr size_t OUT_GO = OUT_GR + (size_t)kNH * kNH;

// ---- merged prep: blocks 0..351 transpose w_fc1 -> wT; blocks 352.. tin scan
__global__ __launch_bounds__(256) void k_prep(const float* __restrict__ w,
                                              const float* __restrict__ x,
                                              float* __restrict__ wT,
                                              float* __restrict__ tin) {
    int bx = blockIdx.x, tid = threadIdx.x;
    if (bx < 352) {
        __shared__ float tile[32][33];
        int i0 = (bx % 22) * 32, r0 = (bx / 22) * 32;
        int tx = tid & 31, ty = tid >> 5;  // 32 x 8
        #pragma unroll
        for (int k = 0; k < 32; k += 8) {
            int i = i0 + tx;
            tile[ty + k][tx] = (i < kNI) ? w[(size_t)(r0 + ty + k) * kNI + i] : 0.f;
        }
        __syncthreads();
        #pragma unroll
        for (int k = 0; k < 32; k += 8) {
            int i = i0 + ty + k;
            wT[(size_t)i * kNH + r0 + tx] = tile[tx][ty + k];
        }
    } else {
        int idx = (bx - 352) * 256 + tid;   // < B*NI
        int b = idx / kNI, i = idx % kNI;
        const float* xp = x + (size_t)b * kT * kNI + i;
        float v = 0.f;
        for (int t = 0; t < kT; t++) {
            v = TAU * v + xp[(size_t)t * kNI];
            tin[(size_t)t * BNI + idx] = v;
        }
    }
}

// ---- XW = Xperm @ wT : C[m=t*64+b, n<512], K=704 (fp32, exact) --------------
__global__ __launch_bounds__(256) void k_xw2(const float* __restrict__ x,
                                             const float* __restrict__ wT,
                                             float* __restrict__ XW) {
    int bx = blockIdx.x;
    int mt = bx % 50, nt = bx / 50;
    int m0 = mt * 128, n0 = nt * 128;
    int tid = threadIdx.x, tx = tid & 15, ty = tid >> 4;
    __shared__ float As[128][20];
    __shared__ float Bs[16][128];
    float acc[8][8] = {};
    int arow = tid >> 1, ahalf = tid & 1;
    int bb = (m0 + arow) & 63, tt = (m0 + arow) >> 6;
    const float* ap = x + ((size_t)bb * kT + tt) * kNI;
    for (int k0 = 0; k0 < kKP; k0 += 16) {
        #pragma unroll
        for (int u = 0; u < 2; u++) {
            int k = k0 + ahalf * 8 + u * 4;
            float4 v = (k + 3 < kNI) ? *(const float4*)(ap + k)
                                     : make_float4(0.f, 0.f, 0.f, 0.f);
            *(float4*)&As[arow][ahalf * 8 + u * 4] = v;
        }
        #pragma unroll
        for (int u = 0; u < 2; u++) {
            int f = tid * 2 + u;
            int kk = f >> 5, c4 = f & 31;
            *(float4*)&Bs[kk][c4 * 4] =
                *(const float4*)(wT + (size_t)(k0 + kk) * kNH + n0 + c4 * 4);
        }
        __syncthreads();
        #pragma unroll
        for (int kk = 0; kk < 16; kk++) {
            float av[8];
            #pragma unroll
            for (int i = 0; i < 4; i++) {
                av[i]     = As[ty * 4 + i][kk];
                av[4 + i] = As[64 + ty * 4 + i][kk];
            }
            float4 b0 = *(const float4*)&Bs[kk][tx * 4];
            float4 b1 = *(const float4*)&Bs[kk][64 + tx * 4];
            float bvv[8] = {b0.x, b0.y, b0.z, b0.w, b1.x, b1.y, b1.z, b1.w};
            #pragma unroll
            for (int i = 0; i < 8; i++)
                #pragma unroll
                for (int j = 0; j < 8; j++) acc[i][j] += av[i] * bvv[j];
        }
        __syncthreads();
    }
    #pragma unroll
    for (int i = 0; i < 8; i++) {
        int m = m0 + ((i < 4) ? (ty * 4 + i) : (64 + ty * 4 + i - 4));
        float* dst = XW + (size_t)m * kNH + n0;
        *(float4*)(dst + tx * 4)      = make_float4(acc[i][0], acc[i][1], acc[i][2], acc[i][3]);
        *(float4*)(dst + 64 + tx * 4) = make_float4(acc[i][4], acc[i][5], acc[i][6], acc[i][7]);
    }
}

// ---- fused forward: ONE block of 832 threads (13 waves) per sample ----------
// Waves 0-7: ROW-sliced gather (R6/R8 structure — measured best): wave w owns
// spike window [64w,64w+64), walks its own mask (ctz), f32x4 loads 16B/lane.
// Waves 8-12: output LIF layer one step behind. 2 barriers/step.
// Tail: errf reverse-scan in LDS + b-major mtb production (no write-amp).
__global__ __launch_bounds__(832) void k_forward(float* __restrict__ ws,
                                                 const float* __restrict__ label,
                                                 const float* __restrict__ w_rec,
                                                 const float* __restrict__ w_out,
                                                 float* __restrict__ dout,
                                                 unsigned long long* __restrict__ gmask) {
    __shared__ float wout_ld[kNO * kNH];          // 40 KB
    __shared__ float partial[8][kNH];             // 16 KB
    __shared__ unsigned long long mh[kT * 8];     // 6.4 KB mask history
    __shared__ float errh[kT * kNO];              // 8 KB err/errf history

    int b = blockIdx.x, tid = threadIdx.x;
    int wave = tid >> 6, lane = tid & 63;
    const f32x4* wr4 = (const f32x4*)w_rec;
    for (int e = tid; e < kNO * kNH; e += 832) wout_ld[e] = w_out[e];
    float hm = 0.f, sp_prev = 0.f;
    float om_r[4] = {0.f, 0.f, 0.f, 0.f}, os_r[4] = {0.f, 0.f, 0.f, 0.f};
    int q = wave - 8;
    const int coff = lane * 2;
    __syncthreads();

    for (int t = 0; t < kT; t++) {
        float xw = 0.f;
        if (wave < 8) {
            xw = ws[O_XW + ((size_t)t * 64 + b) * kNH + tid];
            unsigned long long m = (t > 0) ? mh[(t - 1) * 8 + wave] : 0ull;
            const size_t base = (size_t)wave * 64;
            f32x4 s0 = {0.f, 0.f, 0.f, 0.f}, s1 = s0;
            while (m) {
                int j = __builtin_ctzll(m); m &= m - 1;
                const f32x4* r = wr4 + (base + j) * 128 + coff;
                s0 += r[0]; s1 += r[1];
            }
            *(f32x4*)&partial[wave][lane * 8]     = s0;
            *(f32x4*)&partial[wave][lane * 8 + 4] = s1;
        } else if (t > 0) {
            // output LIF layer for step t-1 (wave q = 0..4)
            int to = t - 1;
            unsigned long long mk[8];
            #pragma unroll
            for (int k = 0; k < 8; k++) mk[k] = mh[to * 8 + k];
            #pragma unroll
            for (int r = 0; r < 4; r++) {
                int o = q * 4 + r;
                float p = 0.f;
                #pragma unroll
                for (int k = 0; k < 8; k++)
                    if ((mk[k] >> lane) & 1) p += wout_ld[o * kNH + 64 * k + lane];
                #pragma unroll
                for (int off = 32; off >= 1; off >>= 1) p += __shfl_xor(p, off);
                if (lane == 0) {
                    float om_n = TAU * om_r[r] * (1.f - os_r[r]) + p;
                    float os_n = (om_n >= THR) ? 1.f : 0.f;
                    om_r[r] = om_n; os_r[r] = os_n;
                    errh[to * kNO + o] = os_n - label[((size_t)b * kT + to) * kNO + o];
                    dout[((size_t)b * kT + to) * kNO + o] = os_n;
                }
            }
        }
        __syncthreads();
        // ---- B: LIF update (threads < 512) ----
        if (tid < kNH) {
            float rec = ((partial[0][tid] + partial[1][tid]) + (partial[2][tid] + partial[3][tid]))
                      + ((partial[4][tid] + partial[5][tid]) + (partial[6][tid] + partial[7][tid]));
            hm = TAU * hm * (1.f - sp_prev) + (xw + rec);
            bool v = (hm >= THR);
            float sp = v ? 1.f : 0.f;
            sp_prev = sp;
            ws[O_HSUR + (size_t)t * BNH + (size_t)b * kNH + tid] =
                TAU * fmaxf(0.f, 1.f - fabsf(hm - THR) * (1.f / THR));
            unsigned long long bal = __ballot(v);
            if (lane == 0) {
                mh[t * 8 + wave] = bal;
                gmask[((size_t)t * 64 + b) * 8 + wave] = bal;
            }
        }
        __syncthreads();
    }
    // ---- tail 1: output layer for t = 99 ----
    if (wave >= 8) {
        int to = kT - 1;
        unsigned long long mk[8];
        #pragma unroll
        for (int k = 0; k < 8; k++) mk[k] = mh[to * 8 + k];
        #pragma unroll
        for (int r = 0; r < 4; r++) {
            int o = q * 4 + r;
            float p = 0.f;
            #pragma unroll
            for (int k = 0; k < 8; k++)
                if ((mk[k] >> lane) & 1) p += wout_ld[o * kNH + 64 * k + lane];
            #pragma unroll
            for (int off = 32; off >= 1; off >>= 1) p += __shfl_xor(p, off);
            if (lane == 0) {
                float om_n = TAU * om_r[r] * (1.f - os_r[r]) + p;
                float os_n = (om_n >= THR) ? 1.f : 0.f;
                errh[to * kNO + o] = os_n - label[((size_t)b * kT + to) * kNO + o];
                dout[((size_t)b * kT + to) * kNO + o] = os_n;
            }
        }
    }
    __syncthreads();
    // ---- tail 2: reverse kappa scan (LDS) + errf -> global (t-major, for go) -
    if (wave == 8 && lane < kNO) {
        float v = 0.f;
        for (int t = kT - 1; t >= 0; t--) {
            v = errh[t * kNO + lane] + TAU_O * v;
            errh[t * kNO + lane] = v;
            ws[O_ERR + (size_t)t * BNO + (size_t)b * kNO + lane] = v;
        }
    }
    __syncthreads();
    // ---- tail 3: mtb[r][b*100+t] = bf16(LR*(errf@w_out)[r]*hsur[t][b][r]) ----
    // b-major k: block b owns a contiguous 200 B span per row -> no cross-XCD
    // partial-line write amplification.
    if (tid < kNH) {
        float wreg[kNO];
        #pragma unroll
        for (int o = 0; o < kNO; o++) wreg[o] = wout_ld[o * kNH + tid];
        unsigned short* mtb = (unsigned short*)(ws + O_MTB);
        size_t rowoff = (size_t)tid * kK + (size_t)b * 100;
        for (int tq = 0; tq < 25; tq++) {
            unsigned long long w8 = 0;
            #pragma unroll
            for (int u = 0; u < 4; u++) {
                int t = tq * 4 + u;
                float s = 0.f;
                #pragma unroll
                for (int o = 0; o < kNO; o++) s += errh[t * kNO + o] * wreg[o];
                float val = LR * s * ws[O_HSUR + (size_t)t * BNH + (size_t)b * kNH + tid];
                __hip_bfloat16 bv = __float2bfloat16(val);
                w8 |= ((unsigned long long)*(unsigned short*)&bv) << (16 * u);
            }
            *(unsigned long long*)&mtb[rowoff + tq * 4] = w8;
        }
    }
}

// ---- merged post: blocks 0..127 densify hs + trb (b-major); rest castT(tin) -
__global__ __launch_bounds__(256) void k_post_cast(float* __restrict__ ws,
                                                   const unsigned long long* __restrict__ gmask) {
    int bx = blockIdx.x, tid = threadIdx.x;
    if (bx < 128) {
        size_t idx = (size_t)bx * 256 + tid;  // < BNH
        {   // dense hs[t+1][b][n] (t-major, for go GEMM)
            int b = (int)(idx >> 9), n = (int)(idx & 511);
            int w = n >> 6, bit = n & 63;
            for (int t = 0; t < kT; t++) {
                float cur = (float)((gmask[((size_t)t * 64 + b) * 8 + w] >> bit) & 1ull);
                ws[O_HS + (size_t)(t + 1) * BNH + idx] = cur;
            }
        }
        {   // trb[n][b*100+t] = bf16(trec), b-major k
            int n = (int)(idx >> 6), b = (int)(idx & 63);
            int w = n >> 6, bit = n & 63;
            __hip_bfloat16* trb = (__hip_bfloat16*)(ws + O_TRB);
            size_t rowoff = (size_t)n * kK + (size_t)b * 100;
            float v = 0.f, p = 0.f;
            for (int t = 0; t < kT; t++) {
                v = TAU * v + p;
                trb[rowoff + t] = __float2bfloat16(v);
                p = (float)((gmask[((size_t)t * 64 + b) * 8 + w] >> bit) & 1ull);
            }
        }
    } else {
        // castT: tib[n][b*100+t] = bf16(tin[t][b][n]), n < 700
        __shared__ float tile[32][33];
        int v = bx - 128;                    // 0..4399 (200 x 22)
        int k0 = (v % 200) * 32, n0 = (v / 200) * 32;
        int tx = tid & 31, ty = tid >> 5;    // 32 x 8
        const float* src = ws + O_TIN;
        __hip_bfloat16* dst = (__hip_bfloat16*)(ws + O_TIB);
        #pragma unroll
        for (int j = 0; j < 32; j += 8) {
            int kk = k0 + ty + j;            // b-major k
            int bb = kk / 100, tt = kk - bb * 100;
            int n = n0 + tx;
            tile[ty + j][tx] = (n < kNI) ? src[(size_t)tt * BNI + (size_t)bb * kNI + n] : 0.f;
        }
        __syncthreads();
        #pragma unroll
        for (int j = 0; j < 32; j += 8) {
            int n = n0 + ty + j;
            if (n < kNI) dst[(size_t)n * kK + k0 + tx] = __float2bfloat16(tile[tx][ty + j]);
        }
    }
}

// ---- merged grads: blocks 0..95 gf (MFMA), 96..159 gr (MFMA), 160..223 go ---
__global__ __launch_bounds__(256) void k_grads(float* __restrict__ ws) {
    __shared__ unsigned short As[128 * 72];   // 18 KB (go path reuses as float)
    __shared__ unsigned short Bs[128 * 72];
    int bx = blockIdx.x, tid = threadIdx.x;

    if (bx < 160) {
        // ---- bf16 MFMA NT GEMM: 128x128 tile, splitK=4, K=6400 (b-major) ----
        constexpr int KC = kK / 4, BK = 64, LDT = 72;
        const unsigned short* A = (const unsigned short*)(ws + O_MTB);
        const unsigned short* B;
        float* Cpart;
        int Nrows, ldc, s, mt, nt;
        if (bx < 96) {
            s = bx & 3; mt = (bx >> 2) & 3; nt = bx >> 4;
            B = (const unsigned short*)(ws + O_TIB);
            Cpart = ws + O_PGF; Nrows = kNI; ldc = 768;
        } else {
            int v = bx - 96;
            s = v & 3; mt = (v >> 2) & 3; nt = v >> 4;
            B = (const unsigned short*)(ws + O_TRB);
            Cpart = ws + O_PGR; Nrows = kNH; ldc = kNH;
        }
        int m0 = mt * 128, n0 = nt * 128, k0 = s * KC;
        int wave = tid >> 6, lane = tid & 63;
        int wm = wave & 1, wn = wave >> 1;
        f32x4 acc[4][4];
        #pragma unroll
        for (int i = 0; i < 4; i++)
            #pragma unroll
            for (int j = 0; j < 4; j++) acc[i][j] = (f32x4){0.f, 0.f, 0.f, 0.f};

        for (int kb = 0; kb < KC; kb += BK) {
            int kg = k0 + kb;
            #pragma unroll
            for (int p = 0; p < 4; p++) {
                int f = tid + p * 256;
                int row = f >> 3, seg = f & 7;
                *(short8*)&As[row * LDT + seg * 8] =
                    *(const short8*)&A[(size_t)(m0 + row) * kK + kg + seg * 8];
                short8 bv = {};
                if (n0 + row < Nrows)
                    bv = *(const short8*)&B[(size_t)(n0 + row) * kK + kg + seg * 8];
                *(short8*)&Bs[row * LDT + seg * 8] = bv;
            }
            __syncthreads();
            #pragma unroll
            for (int h = 0; h < 2; h++) {
                int kof = h * 32 + (lane >> 4) * 8;
                short8 af[4], bf[4];
                #pragma unroll
                for (int i = 0; i < 4; i++)
                    af[i] = *(short8*)&As[(wm * 64 + i * 16 + (lane & 15)) * LDT + kof];
                #pragma unroll
                for (int j = 0; j < 4; j++)
                    bf[j] = *(short8*)&Bs[(wn * 64 + j * 16 + (lane & 15)) * LDT + kof];
                #pragma unroll
                for (int i = 0; i < 4; i++)
                    #pragma unroll
                    for (int j = 0; j < 4; j++)
                        acc[i][j] = __builtin_amdgcn_mfma_f32_16x16x32_bf16(af[i], bf[j], acc[i][j], 0, 0, 0);
            }
            __syncthreads();
        }
        float* C = Cpart + (size_t)s * kNH * ldc;
        int rbase = (lane >> 4) * 4, col = lane & 15;
        #pragma unroll
        for (int i = 0; i < 4; i++)
            #pragma unroll
            for (int j = 0; j < 4; j++) {
                int n = n0 + wn * 64 + j * 16 + col;
                #pragma unroll
                for (int r = 0; r < 4; r++) {
                    int m = m0 + wm * 64 + i * 16 + rbase + r;
                    C[(size_t)m * ldc + n] = acc[i][j][r];
                }
            }
    } else {
        // ---- go: fp32 TN GEMM, M=20, t-major k ----
        float* Asf = (float*)As;   // [16][64]
        float* Bsf = (float*)Bs;   // [16][64]
        const float* A = ws + O_ERR;
        const float* Bm = ws + O_HS + BNH;
        int v = bx - 160;
        int s = v & 7, nt = v >> 3;
        int n0 = nt * 64, k0 = s * 800;
        int tx = tid & 15, ty = tid >> 4;
        float acc[4][4] = {};
        for (int kb = 0; kb < 800; kb += 16) {
            #pragma unroll
            for (int e = tid; e < 1024; e += 256) {
                int kk = e >> 6, c = e & 63;
                size_t gk = (size_t)(k0 + kb + kk);
                Asf[kk * 64 + c] = (c < kNO) ? A[gk * kNO + c] : 0.f;
                Bsf[kk * 64 + c] = Bm[gk * kNH + n0 + c];
            }
            __syncthreads();
            #pragma unroll
            for (int kk = 0; kk < 16; kk++) {
                float4 av = *(const float4*)&Asf[kk * 64 + ty * 4];
                float4 bv = *(const float4*)&Bsf[kk * 64 + tx * 4];
                float aa[4] = {av.x, av.y, av.z, av.w};
                float bb[4] = {bv.x, bv.y, bv.z, bv.w};
                #pragma unroll
                for (int a = 0; a < 4; a++)
                    #pragma unroll
                    for (int c = 0; c < 4; c++) acc[a][c] += aa[a] * bb[c];
            }
            __syncthreads();
        }
        float* Cs = ws + O_PGO + (size_t)s * kNO * kNH;
        #pragma unroll
        for (int a = 0; a < 4; a++) {
            int m = ty * 4 + a;
            if (m >= kNO) continue;
            #pragma unroll
            for (int c = 0; c < 4; c++)
                Cs[(size_t)m * kNH + n0 + tx * 4 + c] = acc[a][c];
        }
    }
}

// ---- merged reduction: gf (4 slices), gr (4 slices), go (8 slices) ----------
__global__ void k_reduce_all(const float* __restrict__ ws, float* __restrict__ dout) {
    int idx = blockIdx.x * 256 + threadIdx.x;  // < 630784
    const int NGF = kNH * kNI, NGR = kNH * kNH, NGO = kNO * kNH;
    float s = 0.f;
    if (idx < NGF) {
        int m = idx / kNI, n = idx - m * kNI;
        size_t src = O_PGF + (size_t)m * 768 + n;
        #pragma unroll
        for (int k = 0; k < 4; k++) s += ws[src + (size_t)k * kNH * 768];
        dout[OUT_GF + idx] = s;   // LR folded into mtb
    } else if (idx < NGF + NGR) {
        int j = idx - NGF;
        #pragma unroll
        for (int k = 0; k < 4; k++) s += ws[O_PGR + j + (size_t)k * NGR];
        dout[OUT_GR + j] = s;
    } else if (idx < NGF + NGR + NGO) {
        int j = idx - NGF - NGR;
        #pragma unroll
        for (int k = 0; k < 8; k++) s += ws[O_PGO + (size_t)k * NGO + j];
        dout[OUT_GO + j] = LR * s;
    }
}

extern "C" void kernel_launch(void* const* d_in, const int* in_sizes, int n_in,
                              void* d_out, int out_size, void* d_ws, size_t ws_size,
                              hipStream_t stream) {
    (void)in_sizes; (void)n_in; (void)out_size;
    const float* x     = (const float*)d_in[0];
    const float* label = (const float*)d_in[1];
    const float* w_fc1 = (const float*)d_in[3];
    const float* w_rec = (const float*)d_in[4];
    const float* w_out = (const float*)d_in[5];
    float* out = (float*)d_out;
    float* ws  = (float*)d_ws;

    if (ws_size < WS_FLOATS * sizeof(float)) return;

    unsigned long long* gmask = (unsigned long long*)(ws + O_MSK);

    k_prep<<<527, 256, 0, stream>>>(w_fc1, x, ws + O_WT, ws + O_TIN);
    k_xw2<<<200, 256, 0, stream>>>(x, ws + O_WT, ws + O_XW);

    k_forward<<<kB, 832, 0, stream>>>(ws, label, w_rec, w_out, out, gmask);

    k_post_cast<<<4528, 256, 0, stream>>>(ws, gmask);   // hs + trb + tib

    k_grads<<<224, 256, 0, stream>>>(ws);               // gf + gr + go in one launch

    k_reduce_all<<<2464, 256, 0, stream>>>(ws, out);
}

// Round 11
// 637.007 us; speedup vs baseline: 1.6038x; 1.0347x over previous
//
#include <hip/hip_runtime.h>
#include <hip/hip_bf16.h>

// Problem constants (B,T,NI,NH,NO fixed by the reference)
constexpr int kB  = 64;
constexpr int kT  = 100;
constexpr int kNI = 700;
constexpr int kNH = 512;
constexpr int kNO = 20;
constexpr float TAU   = 0.6f;
constexpr float TAU_O = 0.6f;
constexpr float THR   = 0.6f;
constexpr float LR    = 0.05f;

constexpr size_t BNH = (size_t)kB * kNH;   // 32768
constexpr size_t BNI = (size_t)kB * kNI;   // 44800
constexpr size_t BNO = (size_t)kB * kNO;   // 1280
constexpr int kK   = kT * kB;              // 6400 (grad-GEMM K; b-major: k = b*100+t)
constexpr int kKP  = 704;                  // padded K for xw GEMM

typedef __attribute__((ext_vector_type(8))) short short8;
typedef __attribute__((ext_vector_type(4))) float f32x4;

// ---------------- workspace layout (float offsets) ---------------------------
// XW dead after k_forward -> PGF/PGR/PGO overlay it. No dense hs (go GEMM
// reads gmask bits directly). TIB has its own region (written pre-forward).
constexpr size_t O_XW   = 0;                                // [T, t*64+b, NH]
constexpr size_t O_PGF  = 0;                                // 4 x [512][768]
constexpr size_t O_PGR  = 1572864;                          // 4 x [512][512]
constexpr size_t O_PGO  = 2621440;                          // 8 x [20][512]
constexpr size_t O_HSUR = 3276800;                          // [T,B,NH]
constexpr size_t O_TIN  = 6553600;                          // [T,B,NI]
constexpr size_t O_ERR  = 11033600;                         // [T,B,NO] errf
constexpr size_t O_WT   = 11161600;                         // [704,512]
constexpr size_t O_MTB  = 11522048;                         // bf16 [512][6400], b-major k
constexpr size_t O_TRB  = 13160448;                         // bf16 [512][6400], b-major k
constexpr size_t O_MSK  = 14798848;                         // u64 [T][B][8] = 102,400 fl
constexpr size_t O_TIB  = 14901248;                         // bf16 [700][6400] = 2,240,000 fl
constexpr size_t WS_FLOATS = 17141248;                      // ~68.6 MB

// d_out layout
constexpr size_t OUT_GF = (size_t)kB * kT * kNO;
constexpr size_t OUT_GR = OUT_GF + (size_t)kNH * kNI;
constexpr size_t OUT_GO = OUT_GR + (size_t)kNH * kNH;

// ---- merged prep: blocks 0..351 transpose w_fc1 -> wT; blocks 352.. tin scan
__global__ __launch_bounds__(256) void k_prep(const float* __restrict__ w,
                                              const float* __restrict__ x,
                                              float* __restrict__ wT,
                                              float* __restrict__ tin) {
    int bx = blockIdx.x, tid = threadIdx.x;
    if (bx < 352) {
        __shared__ float tile[32][33];
        int i0 = (bx % 22) * 32, r0 = (bx / 22) * 32;
        int tx = tid & 31, ty = tid >> 5;  // 32 x 8
        #pragma unroll
        for (int k = 0; k < 32; k += 8) {
            int i = i0 + tx;
            tile[ty + k][tx] = (i < kNI) ? w[(size_t)(r0 + ty + k) * kNI + i] : 0.f;
        }
        __syncthreads();
        #pragma unroll
        for (int k = 0; k < 32; k += 8) {
            int i = i0 + ty + k;
            wT[(size_t)i * kNH + r0 + tx] = tile[tx][ty + k];
        }
    } else {
        int idx = (bx - 352) * 256 + tid;   // < B*NI
        int b = idx / kNI, i = idx % kNI;
        const float* xp = x + (size_t)b * kT * kNI + i;
        float v = 0.f;
        for (int t = 0; t < kT; t++) {
            v = TAU * v + xp[(size_t)t * kNI];
            tin[(size_t)t * BNI + idx] = v;
        }
    }
}

// ---- merged: blocks 0..199 xw GEMM; blocks 200..4599 castT(tin -> tib) ------
__global__ __launch_bounds__(256) void k_xw2c(const float* __restrict__ x,
                                              const float* __restrict__ wT,
                                              float* __restrict__ XW,
                                              const float* __restrict__ tin,
                                              __hip_bfloat16* __restrict__ tib) {
    __shared__ float As[128][20];
    __shared__ float Bs[16][128];
    __shared__ float tile[32][33];
    int bx = blockIdx.x, tid = threadIdx.x;
    if (bx < 200) {
        int mt = bx % 50, nt = bx / 50;
        int m0 = mt * 128, n0 = nt * 128;
        int tx = tid & 15, ty = tid >> 4;
        float acc[8][8] = {};
        int arow = tid >> 1, ahalf = tid & 1;
        int bb = (m0 + arow) & 63, tt = (m0 + arow) >> 6;
        const float* ap = x + ((size_t)bb * kT + tt) * kNI;
        for (int k0 = 0; k0 < kKP; k0 += 16) {
            #pragma unroll
            for (int u = 0; u < 2; u++) {
                int k = k0 + ahalf * 8 + u * 4;
                float4 v = (k + 3 < kNI) ? *(const float4*)(ap + k)
                                         : make_float4(0.f, 0.f, 0.f, 0.f);
                *(float4*)&As[arow][ahalf * 8 + u * 4] = v;
            }
            #pragma unroll
            for (int u = 0; u < 2; u++) {
                int f = tid * 2 + u;
                int kk = f >> 5, c4 = f & 31;
                *(float4*)&Bs[kk][c4 * 4] =
                    *(const float4*)(wT + (size_t)(k0 + kk) * kNH + n0 + c4 * 4);
            }
            __syncthreads();
            #pragma unroll
            for (int kk = 0; kk < 16; kk++) {
                float av[8];
                #pragma unroll
                for (int i = 0; i < 4; i++) {
                    av[i]     = As[ty * 4 + i][kk];
                    av[4 + i] = As[64 + ty * 4 + i][kk];
                }
                float4 b0 = *(const float4*)&Bs[kk][tx * 4];
                float4 b1 = *(const float4*)&Bs[kk][64 + tx * 4];
                float bvv[8] = {b0.x, b0.y, b0.z, b0.w, b1.x, b1.y, b1.z, b1.w};
                #pragma unroll
                for (int i = 0; i < 8; i++)
                    #pragma unroll
                    for (int j = 0; j < 8; j++) acc[i][j] += av[i] * bvv[j];
            }
            __syncthreads();
        }
        #pragma unroll
        for (int i = 0; i < 8; i++) {
            int m = m0 + ((i < 4) ? (ty * 4 + i) : (64 + ty * 4 + i - 4));
            float* dst = XW + (size_t)m * kNH + n0;
            *(float4*)(dst + tx * 4)      = make_float4(acc[i][0], acc[i][1], acc[i][2], acc[i][3]);
            *(float4*)(dst + 64 + tx * 4) = make_float4(acc[i][4], acc[i][5], acc[i][6], acc[i][7]);
        }
    } else {
        // castT: tib[n][b*100+t] = bf16(tin[t][b][n]), n < 700, k b-major
        int v = bx - 200;                    // 0..4399 (200 x 22)
        int k0 = (v % 200) * 32, n0 = (v / 200) * 32;
        int tx = tid & 31, ty = tid >> 5;    // 32 x 8
        #pragma unroll
        for (int j = 0; j < 32; j += 8) {
            int kk = k0 + ty + j;            // b-major k
            int bb = kk / 100, tt = kk - bb * 100;
            int n = n0 + tx;
            tile[ty + j][tx] = (n < kNI) ? tin[(size_t)tt * BNI + (size_t)bb * kNI + n] : 0.f;
        }
        __syncthreads();
        #pragma unroll
        for (int j = 0; j < 32; j += 8) {
            int n = n0 + ty + j;
            if (n < kNI) tib[(size_t)n * kK + k0 + tx] = __float2bfloat16(tile[tx][ty + j]);
        }
    }
}

// ---- fused forward: ONE block of 832 threads (13 waves) per sample ----------
// Waves 0-7: row-sliced gather (measured best). Waves 8-12: output LIF layer
// one step behind. 2 barriers/step. Tail: trb (from LDS mask history), errf
// reverse-scan, b-major mtb. No dense hs anywhere.
__global__ __launch_bounds__(832) void k_forward(float* __restrict__ ws,
                                                 const float* __restrict__ label,
                                                 const float* __restrict__ w_rec,
                                                 const float* __restrict__ w_out,
                                                 float* __restrict__ dout,
                                                 unsigned long long* __restrict__ gmask) {
    __shared__ float wout_ld[kNO * kNH];          // 40 KB
    __shared__ float partial[8][kNH];             // 16 KB
    __shared__ unsigned long long mh[kT * 8];     // 6.4 KB mask history
    __shared__ float errh[kT * kNO];              // 8 KB err/errf history

    int b = blockIdx.x, tid = threadIdx.x;
    int wave = tid >> 6, lane = tid & 63;
    const f32x4* wr4 = (const f32x4*)w_rec;
    for (int e = tid; e < kNO * kNH; e += 832) wout_ld[e] = w_out[e];
    float hm = 0.f, sp_prev = 0.f;
    float om_r[4] = {0.f, 0.f, 0.f, 0.f}, os_r[4] = {0.f, 0.f, 0.f, 0.f};
    int q = wave - 8;
    const int coff = lane * 2;
    __syncthreads();

    for (int t = 0; t < kT; t++) {
        float xw = 0.f;
        if (wave < 8) {
            xw = ws[O_XW + ((size_t)t * 64 + b) * kNH + tid];
            unsigned long long m = (t > 0) ? mh[(t - 1) * 8 + wave] : 0ull;
            const size_t base = (size_t)wave * 64;
            f32x4 s0 = {0.f, 0.f, 0.f, 0.f}, s1 = s0;
            while (m) {
                int j = __builtin_ctzll(m); m &= m - 1;
                const f32x4* r = wr4 + (base + j) * 128 + coff;
                s0 += r[0]; s1 += r[1];
            }
            *(f32x4*)&partial[wave][lane * 8]     = s0;
            *(f32x4*)&partial[wave][lane * 8 + 4] = s1;
        } else if (t > 0) {
            // output LIF layer for step t-1 (wave q = 0..4)
            int to = t - 1;
            unsigned long long mk[8];
            #pragma unroll
            for (int k = 0; k < 8; k++) mk[k] = mh[to * 8 + k];
            #pragma unroll
            for (int r = 0; r < 4; r++) {
                int o = q * 4 + r;
                float p = 0.f;
                #pragma unroll
                for (int k = 0; k < 8; k++)
                    if ((mk[k] >> lane) & 1) p += wout_ld[o * kNH + 64 * k + lane];
                #pragma unroll
                for (int off = 32; off >= 1; off >>= 1) p += __shfl_xor(p, off);
                if (lane == 0) {
                    float om_n = TAU * om_r[r] * (1.f - os_r[r]) + p;
                    float os_n = (om_n >= THR) ? 1.f : 0.f;
                    om_r[r] = om_n; os_r[r] = os_n;
                    errh[to * kNO + o] = os_n - label[((size_t)b * kT + to) * kNO + o];
                    dout[((size_t)b * kT + to) * kNO + o] = os_n;
                }
            }
        }
        __syncthreads();
        // ---- B: LIF update (threads < 512) ----
        if (tid < kNH) {
            float rec = ((partial[0][tid] + partial[1][tid]) + (partial[2][tid] + partial[3][tid]))
                      + ((partial[4][tid] + partial[5][tid]) + (partial[6][tid] + partial[7][tid]));
            hm = TAU * hm * (1.f - sp_prev) + (xw + rec);
            bool v = (hm >= THR);
            float sp = v ? 1.f : 0.f;
            sp_prev = sp;
            ws[O_HSUR + (size_t)t * BNH + (size_t)b * kNH + tid] =
                TAU * fmaxf(0.f, 1.f - fabsf(hm - THR) * (1.f / THR));
            unsigned long long bal = __ballot(v);
            if (lane == 0) {
                mh[t * 8 + wave] = bal;
                gmask[((size_t)t * 64 + b) * 8 + wave] = bal;
            }
        }
        __syncthreads();
    }
    // ---- tail 1a: output layer for t = 99 (waves 8..12) ----
    if (wave >= 8) {
        int to = kT - 1;
        unsigned long long mk[8];
        #pragma unroll
        for (int k = 0; k < 8; k++) mk[k] = mh[to * 8 + k];
        #pragma unroll
        for (int r = 0; r < 4; r++) {
            int o = q * 4 + r;
            float p = 0.f;
            #pragma unroll
            for (int k = 0; k < 8; k++)
                if ((mk[k] >> lane) & 1) p += wout_ld[o * kNH + 64 * k + lane];
            #pragma unroll
            for (int off = 32; off >= 1; off >>= 1) p += __shfl_xor(p, off);
            if (lane == 0) {
                float om_n = TAU * om_r[r] * (1.f - os_r[r]) + p;
                float os_n = (om_n >= THR) ? 1.f : 0.f;
                errh[to * kNO + o] = os_n - label[((size_t)b * kT + to) * kNO + o];
                dout[((size_t)b * kT + to) * kNO + o] = os_n;
            }
        }
    }
    // ---- tail 1b (concurrent): trb[n][b*100+t] = bf16(trec) from mh ---------
    if (tid < kNH) {
        unsigned short* trb = (unsigned short*)(ws + O_TRB);
        size_t rowoff = (size_t)tid * kK + (size_t)b * 100;
        int w = tid >> 6, bit = tid & 63;
        float v = 0.f, p = 0.f;
        for (int tq = 0; tq < 25; tq++) {
            unsigned long long w8 = 0;
            #pragma unroll
            for (int u = 0; u < 4; u++) {
                int t = tq * 4 + u;
                v = TAU * v + p;
                __hip_bfloat16 bv = __float2bfloat16(v);
                w8 |= ((unsigned long long)*(unsigned short*)&bv) << (16 * u);
                p = (float)((mh[t * 8 + w] >> bit) & 1ull);
            }
            *(unsigned long long*)&trb[rowoff + tq * 4] = w8;
        }
    }
    __syncthreads();
    // ---- tail 2: reverse kappa scan (LDS) + errf -> global (t-major, for go) -
    if (wave == 8 && lane < kNO) {
        float v = 0.f;
        for (int t = kT - 1; t >= 0; t--) {
            v = errh[t * kNO + lane] + TAU_O * v;
            errh[t * kNO + lane] = v;
            ws[O_ERR + (size_t)t * BNO + (size_t)b * kNO + lane] = v;
        }
    }
    __syncthreads();
    // ---- tail 3: mtb[r][b*100+t] = bf16(LR*(errf@w_out)[r]*hsur[t][b][r]) ----
    if (tid < kNH) {
        float wreg[kNO];
        #pragma unroll
        for (int o = 0; o < kNO; o++) wreg[o] = wout_ld[o * kNH + tid];
        unsigned short* mtb = (unsigned short*)(ws + O_MTB);
        size_t rowoff = (size_t)tid * kK + (size_t)b * 100;
        for (int tq = 0; tq < 25; tq++) {
            unsigned long long w8 = 0;
            #pragma unroll
            for (int u = 0; u < 4; u++) {
                int t = tq * 4 + u;
                float s = 0.f;
                #pragma unroll
                for (int o = 0; o < kNO; o++) s += errh[t * kNO + o] * wreg[o];
                float val = LR * s * ws[O_HSUR + (size_t)t * BNH + (size_t)b * kNH + tid];
                __hip_bfloat16 bv = __float2bfloat16(val);
                w8 |= ((unsigned long long)*(unsigned short*)&bv) << (16 * u);
            }
            *(unsigned long long*)&mtb[rowoff + tq * 4] = w8;
        }
    }
}

// ---- merged grads: blocks 0..95 gf (MFMA), 96..159 gr (MFMA), 160..223 go ---
__global__ __launch_bounds__(256) void k_grads(float* __restrict__ ws) {
    __shared__ unsigned short As[128 * 72];   // go path reuses as float
    __shared__ unsigned short Bs[128 * 72];
    int bx = blockIdx.x, tid = threadIdx.x;

    if (bx < 160) {
        // ---- bf16 MFMA NT GEMM: 128x128 tile, splitK=4, K=6400 (b-major) ----
        constexpr int KC = kK / 4, BK = 64, LDT = 72;
        const unsigned short* A = (const unsigned short*)(ws + O_MTB);
        const unsigned short* B;
        float* Cpart;
        int Nrows, ldc, s, mt, nt;
        if (bx < 96) {
            s = bx & 3; mt = (bx >> 2) & 3; nt = bx >> 4;
            B = (const unsigned short*)(ws + O_TIB);
            Cpart = ws + O_PGF; Nrows = kNI; ldc = 768;
        } else {
            int v = bx - 96;
            s = v & 3; mt = (v >> 2) & 3; nt = v >> 4;
            B = (const unsigned short*)(ws + O_TRB);
            Cpart = ws + O_PGR; Nrows = kNH; ldc = kNH;
        }
        int m0 = mt * 128, n0 = nt * 128, k0 = s * KC;
        int wave = tid >> 6, lane = tid & 63;
        int wm = wave & 1, wn = wave >> 1;
        f32x4 acc[4][4];
        #pragma unroll
        for (int i = 0; i < 4; i++)
            #pragma unroll
            for (int j = 0; j < 4; j++) acc[i][j] = (f32x4){0.f, 0.f, 0.f, 0.f};

        for (int kb = 0; kb < KC; kb += BK) {
            int kg = k0 + kb;
            #pragma unroll
            for (int p = 0; p < 4; p++) {
                int f = tid + p * 256;
                int row = f >> 3, seg = f & 7;
                *(short8*)&As[row * LDT + seg * 8] =
                    *(const short8*)&A[(size_t)(m0 + row) * kK + kg + seg * 8];
                short8 bv = {};
                if (n0 + row < Nrows)
                    bv = *(const short8*)&B[(size_t)(n0 + row) * kK + kg + seg * 8];
                *(short8*)&Bs[row * LDT + seg * 8] = bv;
            }
            __syncthreads();
            #pragma unroll
            for (int h = 0; h < 2; h++) {
                int kof = h * 32 + (lane >> 4) * 8;
                short8 af[4], bf[4];
                #pragma unroll
                for (int i = 0; i < 4; i++)
                    af[i] = *(short8*)&As[(wm * 64 + i * 16 + (lane & 15)) * LDT + kof];
                #pragma unroll
                for (int j = 0; j < 4; j++)
                    bf[j] = *(short8*)&Bs[(wn * 64 + j * 16 + (lane & 15)) * LDT + kof];
                #pragma unroll
                for (int i = 0; i < 4; i++)
                    #pragma unroll
                    for (int j = 0; j < 4; j++)
                        acc[i][j] = __builtin_amdgcn_mfma_f32_16x16x32_bf16(af[i], bf[j], acc[i][j], 0, 0, 0);
            }
            __syncthreads();
        }
        float* C = Cpart + (size_t)s * kNH * ldc;
        int rbase = (lane >> 4) * 4, col = lane & 15;
        #pragma unroll
        for (int i = 0; i < 4; i++)
            #pragma unroll
            for (int j = 0; j < 4; j++) {
                int n = n0 + wn * 64 + j * 16 + col;
                #pragma unroll
                for (int r = 0; r < 4; r++) {
                    int m = m0 + wm * 64 + i * 16 + rbase + r;
                    C[(size_t)m * ldc + n] = acc[i][j][r];
                }
            }
    } else {
        // ---- go: fp32 TN GEMM, M=20, t-major k; B bits straight from gmask --
        float* Asf = (float*)As;   // [16][64]
        float* Bsf = (float*)Bs;   // [16][64]
        const float* A = ws + O_ERR;
        const unsigned long long* gm = (const unsigned long long*)(ws + O_MSK);
        int v = bx - 160;
        int s = v & 7, nt = v >> 3;
        int n0 = nt * 64, k0 = s * 800;
        int w0 = n0 >> 6;                  // one mask word per k-row for this n-tile
        int tx = tid & 15, ty = tid >> 4;
        float acc[4][4] = {};
        for (int kb = 0; kb < 800; kb += 16) {
            #pragma unroll
            for (int e = tid; e < 1024; e += 256) {
                int kk = e >> 6, c = e & 63;
                size_t gk = (size_t)(k0 + kb + kk);
                Asf[kk * 64 + c] = (c < kNO) ? A[gk * kNO + c] : 0.f;
                Bsf[kk * 64 + c] = (float)((gm[gk * 8 + w0] >> c) & 1ull);
            }
            __syncthreads();
            #pragma unroll
            for (int kk = 0; kk < 16; kk++) {
                float4 av = *(const float4*)&Asf[kk * 64 + ty * 4];
                float4 bv = *(const float4*)&Bsf[kk * 64 + tx * 4];
                float aa[4] = {av.x, av.y, av.z, av.w};
                float bb[4] = {bv.x, bv.y, bv.z, bv.w};
                #pragma unroll
                for (int a = 0; a < 4; a++)
                    #pragma unroll
                    for (int c = 0; c < 4; c++) acc[a][c] += aa[a] * bb[c];
            }
            __syncthreads();
        }
        float* Cs = ws + O_PGO + (size_t)s * kNO * kNH;
        #pragma unroll
        for (int a = 0; a < 4; a++) {
            int m = ty * 4 + a;
            if (m >= kNO) continue;
            #pragma unroll
            for (int c = 0; c < 4; c++)
                Cs[(size_t)m * kNH + n0 + tx * 4 + c] = acc[a][c];
        }
    }
}

// ---- merged reduction: gf (4 slices), gr (4 slices), go (8 slices) ----------
__global__ void k_reduce_all(const float* __restrict__ ws, float* __restrict__ dout) {
    int idx = blockIdx.x * 256 + threadIdx.x;  // < 630784
    const int NGF = kNH * kNI, NGR = kNH * kNH, NGO = kNO * kNH;
    float s = 0.f;
    if (idx < NGF) {
        int m = idx / kNI, n = idx - m * kNI;
        size_t src = O_PGF + (size_t)m * 768 + n;
        #pragma unroll
        for (int k = 0; k < 4; k++) s += ws[src + (size_t)k * kNH * 768];
        dout[OUT_GF + idx] = s;   // LR folded into mtb
    } else if (idx < NGF + NGR) {
        int j = idx - NGF;
        #pragma unroll
        for (int k = 0; k < 4; k++) s += ws[O_PGR + j + (size_t)k * NGR];
        dout[OUT_GR + j] = s;
    } else if (idx < NGF + NGR + NGO) {
        int j = idx - NGF - NGR;
        #pragma unroll
        for (int k = 0; k < 8; k++) s += ws[O_PGO + (size_t)k * NGO + j];
        dout[OUT_GO + j] = LR * s;
    }
}

extern "C" void kernel_launch(void* const* d_in, const int* in_sizes, int n_in,
                              void* d_out, int out_size, void* d_ws, size_t ws_size,
                              hipStream_t stream) {
    (void)in_sizes; (void)n_in; (void)out_size;
    const float* x     = (const float*)d_in[0];
    const float* label = (const float*)d_in[1];
    const float* w_fc1 = (const float*)d_in[3];
    const float* w_rec = (const float*)d_in[4];
    const float* w_out = (const float*)d_in[5];
    float* out = (float*)d_out;
    float* ws  = (float*)d_ws;

    if (ws_size < WS_FLOATS * sizeof(float)) return;

    __hip_bfloat16* tib = (__hip_bfloat16*)(ws + O_TIB);
    unsigned long long* gmask = (unsigned long long*)(ws + O_MSK);

    k_prep<<<527, 256, 0, stream>>>(w_fc1, x, ws + O_WT, ws + O_TIN);
    k_xw2c<<<4600, 256, 0, stream>>>(x, ws + O_WT, ws + O_XW, ws + O_TIN, tib);

    k_forward<<<kB, 832, 0, stream>>>(ws, label, w_rec, w_out, out, gmask);

    k_grads<<<224, 256, 0, stream>>>(ws);               // gf + gr + go in one launch

    k_reduce_all<<<2464, 256, 0, stream>>>(ws, out);
}

// Round 12
// 634.006 us; speedup vs baseline: 1.6113x; 1.0047x over previous
//
#include <hip/hip_runtime.h>
#include <hip/hip_bf16.h>

// Problem constants (B,T,NI,NH,NO fixed by the reference)
constexpr int kB  = 64;
constexpr int kT  = 100;
constexpr int kNI = 700;
constexpr int kNH = 512;
constexpr int kNO = 20;
constexpr float TAU   = 0.6f;
constexpr float TAU_O = 0.6f;
constexpr float THR   = 0.6f;
constexpr float LR    = 0.05f;

constexpr size_t BNH = (size_t)kB * kNH;   // 32768
constexpr size_t BNI = (size_t)kB * kNI;   // 44800
constexpr size_t BNO = (size_t)kB * kNO;   // 1280
constexpr int kK   = kT * kB;              // 6400 (grad-GEMM K; b-major: k = b*100+t)
constexpr int kKP  = 704;                  // padded K for xw GEMM

typedef __attribute__((ext_vector_type(8))) short short8;
typedef __attribute__((ext_vector_type(4))) float f32x4;

// ---------------- workspace layout (float offsets) ---------------------------
// XW dead after k_forward -> PGF/PGR/PGO overlay it. No dense tin/hs/wT.
constexpr size_t O_XW   = 0;                                // [T, t*64+b, NH] 3,276,800
constexpr size_t O_PGF  = 0;                                // 4 x [512][768]
constexpr size_t O_PGR  = 1572864;                          // 4 x [512][512]
constexpr size_t O_PGO  = 2621440;                          // 8 x [20][512] (ends 2,703,360)
constexpr size_t O_HSUR = 3276800;                          // [T,B,NH] 3,276,800
constexpr size_t O_ERR  = 6553600;                          // [T,B,NO] errf 128,000
constexpr size_t O_MTB  = 6681600;                          // bf16 [512][6400], b-major k
constexpr size_t O_TRB  = 8320000;                          // bf16 [512][6400], b-major k
constexpr size_t O_MSK  = 9958400;                          // u64 [T][B][8] = 102,400 fl
constexpr size_t O_TIB  = 10060800;                         // bf16 [700][6400] = 2,240,000 fl
constexpr size_t WS_FLOATS = 12300800;                      // ~49.2 MB

// d_out layout
constexpr size_t OUT_GF = (size_t)kB * kT * kNO;
constexpr size_t OUT_GR = OUT_GF + (size_t)kNH * kNI;
constexpr size_t OUT_GO = OUT_GR + (size_t)kNH * kNH;

// ---- XW = Xperm @ w_fc1^T : C[m=t*64+b, n<512], K=704 (fp32, exact) ---------
// B-tile staged directly from w_fc1 rows (K-contiguous) with transpose-in-LDS;
// Bs values identical to the old wT path -> XW bit-identical.
__global__ __launch_bounds__(256) void k_xw2(const float* __restrict__ x,
                                             const float* __restrict__ wfc,
                                             float* __restrict__ XW) {
    int bx = blockIdx.x;
    int mt = bx % 50, nt = bx / 50;
    int m0 = mt * 128, n0 = nt * 128;
    int tid = threadIdx.x, tx = tid & 15, ty = tid >> 4;
    __shared__ float As[128][20];
    __shared__ float Bs[16][128];
    float acc[8][8] = {};
    int arow = tid >> 1, ahalf = tid & 1;
    int bb = (m0 + arow) & 63, tt = (m0 + arow) >> 6;
    const float* ap = x + ((size_t)bb * kT + tt) * kNI;
    const float* wp = wfc + (size_t)(n0 + arow) * kNI;
    for (int k0 = 0; k0 < kKP; k0 += 16) {
        #pragma unroll
        for (int u = 0; u < 2; u++) {
            int k = k0 + ahalf * 8 + u * 4;
            float4 v = (k + 3 < kNI) ? *(const float4*)(ap + k)
                                     : make_float4(0.f, 0.f, 0.f, 0.f);
            *(float4*)&As[arow][ahalf * 8 + u * 4] = v;
        }
        {
            int kb = k0 + ahalf * 8;
            float4 v0 = (kb + 3 < kNI) ? *(const float4*)(wp + kb)
                                       : make_float4(0.f, 0.f, 0.f, 0.f);
            float4 v1 = (kb + 7 < kNI) ? *(const float4*)(wp + kb + 4)
                                       : make_float4(0.f, 0.f, 0.f, 0.f);
            int c = ahalf * 8;
            Bs[c + 0][arow] = v0.x; Bs[c + 1][arow] = v0.y;
            Bs[c + 2][arow] = v0.z; Bs[c + 3][arow] = v0.w;
            Bs[c + 4][arow] = v1.x; Bs[c + 5][arow] = v1.y;
            Bs[c + 6][arow] = v1.z; Bs[c + 7][arow] = v1.w;
        }
        __syncthreads();
        #pragma unroll
        for (int kk = 0; kk < 16; kk++) {
            float av[8];
            #pragma unroll
            for (int i = 0; i < 4; i++) {
                av[i]     = As[ty * 4 + i][kk];
                av[4 + i] = As[64 + ty * 4 + i][kk];
            }
            float4 b0 = *(const float4*)&Bs[kk][tx * 4];
            float4 b1 = *(const float4*)&Bs[kk][64 + tx * 4];
            float bvv[8] = {b0.x, b0.y, b0.z, b0.w, b1.x, b1.y, b1.z, b1.w};
            #pragma unroll
            for (int i = 0; i < 8; i++)
                #pragma unroll
                for (int j = 0; j < 8; j++) acc[i][j] += av[i] * bvv[j];
        }
        __syncthreads();
    }
    #pragma unroll
    for (int i = 0; i < 8; i++) {
        int m = m0 + ((i < 4) ? (ty * 4 + i) : (64 + ty * 4 + i - 4));
        float* dst = XW + (size_t)m * kNH + n0;
        *(float4*)(dst + tx * 4)      = make_float4(acc[i][0], acc[i][1], acc[i][2], acc[i][3]);
        *(float4*)(dst + 64 + tx * 4) = make_float4(acc[i][4], acc[i][5], acc[i][6], acc[i][7]);
    }
}

// ---- fused forward + hidden tib cast ----------------------------------------
// Blocks 0..63: one block of 832 threads per sample (row-sliced gather waves
// 0-7, output LIF on waves 8-12, 2 barriers/step; tails: trb, errf scan, mtb).
// Blocks 64..117: direct x -> tib bf16 scan (b-major k) on otherwise-idle CUs.
__global__ __launch_bounds__(832) void k_forward(float* __restrict__ ws,
                                                 const float* __restrict__ label,
                                                 const float* __restrict__ w_rec,
                                                 const float* __restrict__ w_out,
                                                 float* __restrict__ dout,
                                                 unsigned long long* __restrict__ gmask,
                                                 const float* __restrict__ x) {
    __shared__ float wout_ld[kNO * kNH];          // 40 KB
    __shared__ float partial[8][kNH];             // 16 KB
    __shared__ unsigned long long mh[kT * 8];     // 6.4 KB mask history
    __shared__ float errh[kT * kNO];              // 8 KB err/errf history

    int bxg = blockIdx.x, tid = threadIdx.x;
    if (bxg >= kB) {
        // ---- tib[n=i][b*100+t] = bf16(tin scan of x) — hidden under forward --
        int idx = (bxg - kB) * 832 + tid;
        if (idx < (int)BNI) {
            int b = idx / kNI, i = idx - b * kNI;
            const float* xp = x + (size_t)b * kT * kNI + i;
            unsigned short* tib = (unsigned short*)(ws + O_TIB);
            size_t rowoff = (size_t)i * kK + (size_t)b * 100;
            float v = 0.f;
            for (int tq = 0; tq < 25; tq++) {
                unsigned long long w8 = 0;
                #pragma unroll
                for (int u = 0; u < 4; u++) {
                    int t = tq * 4 + u;
                    v = TAU * v + xp[(size_t)t * kNI];
                    __hip_bfloat16 bv = __float2bfloat16(v);
                    w8 |= ((unsigned long long)*(unsigned short*)&bv) << (16 * u);
                }
                *(unsigned long long*)&tib[rowoff + tq * 4] = w8;
            }
        }
        return;
    }

    int b = bxg;
    int wave = tid >> 6, lane = tid & 63;
    const f32x4* wr4 = (const f32x4*)w_rec;
    for (int e = tid; e < kNO * kNH; e += 832) wout_ld[e] = w_out[e];
    float hm = 0.f, sp_prev = 0.f;
    float om_r[4] = {0.f, 0.f, 0.f, 0.f}, os_r[4] = {0.f, 0.f, 0.f, 0.f};
    int q = wave - 8;
    const int coff = lane * 2;
    __syncthreads();

    for (int t = 0; t < kT; t++) {
        float xw = 0.f;
        if (wave < 8) {
            xw = ws[O_XW + ((size_t)t * 64 + b) * kNH + tid];
            unsigned long long m = (t > 0) ? mh[(t - 1) * 8 + wave] : 0ull;
            const size_t base = (size_t)wave * 64;
            f32x4 s0 = {0.f, 0.f, 0.f, 0.f}, s1 = s0;
            while (m) {
                int j = __builtin_ctzll(m); m &= m - 1;
                const f32x4* r = wr4 + (base + j) * 128 + coff;
                s0 += r[0]; s1 += r[1];
            }
            *(f32x4*)&partial[wave][lane * 8]     = s0;
            *(f32x4*)&partial[wave][lane * 8 + 4] = s1;
        } else if (t > 0) {
            // output LIF layer for step t-1 (wave q = 0..4)
            int to = t - 1;
            unsigned long long mk[8];
            #pragma unroll
            for (int k = 0; k < 8; k++) mk[k] = mh[to * 8 + k];
            #pragma unroll
            for (int r = 0; r < 4; r++) {
                int o = q * 4 + r;
                float p = 0.f;
                #pragma unroll
                for (int k = 0; k < 8; k++)
                    if ((mk[k] >> lane) & 1) p += wout_ld[o * kNH + 64 * k + lane];
                #pragma unroll
                for (int off = 32; off >= 1; off >>= 1) p += __shfl_xor(p, off);
                if (lane == 0) {
                    float om_n = TAU * om_r[r] * (1.f - os_r[r]) + p;
                    float os_n = (om_n >= THR) ? 1.f : 0.f;
                    om_r[r] = om_n; os_r[r] = os_n;
                    errh[to * kNO + o] = os_n - label[((size_t)b * kT + to) * kNO + o];
                    dout[((size_t)b * kT + to) * kNO + o] = os_n;
                }
            }
        }
        __syncthreads();
        // ---- B: LIF update (threads < 512) ----
        if (tid < kNH) {
            float rec = ((partial[0][tid] + partial[1][tid]) + (partial[2][tid] + partial[3][tid]))
                      + ((partial[4][tid] + partial[5][tid]) + (partial[6][tid] + partial[7][tid]));
            hm = TAU * hm * (1.f - sp_prev) + (xw + rec);
            bool v = (hm >= THR);
            float sp = v ? 1.f : 0.f;
            sp_prev = sp;
            ws[O_HSUR + (size_t)t * BNH + (size_t)b * kNH + tid] =
                TAU * fmaxf(0.f, 1.f - fabsf(hm - THR) * (1.f / THR));
            unsigned long long bal = __ballot(v);
            if (lane == 0) {
                mh[t * 8 + wave] = bal;
                gmask[((size_t)t * 64 + b) * 8 + wave] = bal;
            }
        }
        __syncthreads();
    }
    // ---- tail 1a: output layer for t = 99 (waves 8..12) ----
    if (wave >= 8) {
        int to = kT - 1;
        unsigned long long mk[8];
        #pragma unroll
        for (int k = 0; k < 8; k++) mk[k] = mh[to * 8 + k];
        #pragma unroll
        for (int r = 0; r < 4; r++) {
            int o = q * 4 + r;
            float p = 0.f;
            #pragma unroll
            for (int k = 0; k < 8; k++)
                if ((mk[k] >> lane) & 1) p += wout_ld[o * kNH + 64 * k + lane];
            #pragma unroll
            for (int off = 32; off >= 1; off >>= 1) p += __shfl_xor(p, off);
            if (lane == 0) {
                float om_n = TAU * om_r[r] * (1.f - os_r[r]) + p;
                float os_n = (om_n >= THR) ? 1.f : 0.f;
                errh[to * kNO + o] = os_n - label[((size_t)b * kT + to) * kNO + o];
                dout[((size_t)b * kT + to) * kNO + o] = os_n;
            }
        }
    }
    // ---- tail 1b (concurrent): trb[n][b*100+t] = bf16(trec) from mh ---------
    if (tid < kNH) {
        unsigned short* trb = (unsigned short*)(ws + O_TRB);
        size_t rowoff = (size_t)tid * kK + (size_t)b * 100;
        int w = tid >> 6, bit = tid & 63;
        float v = 0.f, p = 0.f;
        for (int tq = 0; tq < 25; tq++) {
            unsigned long long w8 = 0;
            #pragma unroll
            for (int u = 0; u < 4; u++) {
                int t = tq * 4 + u;
                v = TAU * v + p;
                __hip_bfloat16 bv = __float2bfloat16(v);
                w8 |= ((unsigned long long)*(unsigned short*)&bv) << (16 * u);
                p = (float)((mh[t * 8 + w] >> bit) & 1ull);
            }
            *(unsigned long long*)&trb[rowoff + tq * 4] = w8;
        }
    }
    __syncthreads();
    // ---- tail 2: reverse kappa scan (LDS) + errf -> global (t-major, for go) -
    if (wave == 8 && lane < kNO) {
        float v = 0.f;
        for (int t = kT - 1; t >= 0; t--) {
            v = errh[t * kNO + lane] + TAU_O * v;
            errh[t * kNO + lane] = v;
            ws[O_ERR + (size_t)t * BNO + (size_t)b * kNO + lane] = v;
        }
    }
    __syncthreads();
    // ---- tail 3: mtb[r][b*100+t] = bf16(LR*(errf@w_out)[r]*hsur[t][b][r]) ----
    if (tid < kNH) {
        float wreg[kNO];
        #pragma unroll
        for (int o = 0; o < kNO; o++) wreg[o] = wout_ld[o * kNH + tid];
        unsigned short* mtb = (unsigned short*)(ws + O_MTB);
        size_t rowoff = (size_t)tid * kK + (size_t)b * 100;
        for (int tq = 0; tq < 25; tq++) {
            unsigned long long w8 = 0;
            #pragma unroll
            for (int u = 0; u < 4; u++) {
                int t = tq * 4 + u;
                float s = 0.f;
                #pragma unroll
                for (int o = 0; o < kNO; o++) s += errh[t * kNO + o] * wreg[o];
                float val = LR * s * ws[O_HSUR + (size_t)t * BNH + (size_t)b * kNH + tid];
                __hip_bfloat16 bv = __float2bfloat16(val);
                w8 |= ((unsigned long long)*(unsigned short*)&bv) << (16 * u);
            }
            *(unsigned long long*)&mtb[rowoff + tq * 4] = w8;
        }
    }
}

// ---- merged grads: blocks 0..95 gf (MFMA), 96..159 gr (MFMA), 160..223 go ---
__global__ __launch_bounds__(256) void k_grads(float* __restrict__ ws) {
    __shared__ unsigned short As[128 * 72];   // go path reuses as float
    __shared__ unsigned short Bs[128 * 72];
    int bx = blockIdx.x, tid = threadIdx.x;

    if (bx < 160) {
        constexpr int KC = kK / 4, BK = 64, LDT = 72;
        const unsigned short* A = (const unsigned short*)(ws + O_MTB);
        const unsigned short* B;
        float* Cpart;
        int Nrows, ldc, s, mt, nt;
        if (bx < 96) {
            s = bx & 3; mt = (bx >> 2) & 3; nt = bx >> 4;
            B = (const unsigned short*)(ws + O_TIB);
            Cpart = ws + O_PGF; Nrows = kNI; ldc = 768;
        } else {
            int v = bx - 96;
            s = v & 3; mt = (v >> 2) & 3; nt = v >> 4;
            B = (const unsigned short*)(ws + O_TRB);
            Cpart = ws + O_PGR; Nrows = kNH; ldc = kNH;
        }
        int m0 = mt * 128, n0 = nt * 128, k0 = s * KC;
        int wave = tid >> 6, lane = tid & 63;
        int wm = wave & 1, wn = wave >> 1;
        f32x4 acc[4][4];
        #pragma unroll
        for (int i = 0; i < 4; i++)
            #pragma unroll
            for (int j = 0; j < 4; j++) acc[i][j] = (f32x4){0.f, 0.f, 0.f, 0.f};

        for (int kb = 0; kb < KC; kb += BK) {
            int kg = k0 + kb;
            #pragma unroll
            for (int p = 0; p < 4; p++) {
                int f = tid + p * 256;
                int row = f >> 3, seg = f & 7;
                *(short8*)&As[row * LDT + seg * 8] =
                    *(const short8*)&A[(size_t)(m0 + row) * kK + kg + seg * 8];
                short8 bv = {};
                if (n0 + row < Nrows)
                    bv = *(const short8*)&B[(size_t)(n0 + row) * kK + kg + seg * 8];
                *(short8*)&Bs[row * LDT + seg * 8] = bv;
            }
            __syncthreads();
            #pragma unroll
            for (int h = 0; h < 2; h++) {
                int kof = h * 32 + (lane >> 4) * 8;
                short8 af[4], bf[4];
                #pragma unroll
                for (int i = 0; i < 4; i++)
                    af[i] = *(short8*)&As[(wm * 64 + i * 16 + (lane & 15)) * LDT + kof];
                #pragma unroll
                for (int j = 0; j < 4; j++)
                    bf[j] = *(short8*)&Bs[(wn * 64 + j * 16 + (lane & 15)) * LDT + kof];
                #pragma unroll
                for (int i = 0; i < 4; i++)
                    #pragma unroll
                    for (int j = 0; j < 4; j++)
                        acc[i][j] = __builtin_amdgcn_mfma_f32_16x16x32_bf16(af[i], bf[j], acc[i][j], 0, 0, 0);
            }
            __syncthreads();
        }
        float* C = Cpart + (size_t)s * kNH * ldc;
        int rbase = (lane >> 4) * 4, col = lane & 15;
        #pragma unroll
        for (int i = 0; i < 4; i++)
            #pragma unroll
            for (int j = 0; j < 4; j++) {
                int n = n0 + wn * 64 + j * 16 + col;
                #pragma unroll
                for (int r = 0; r < 4; r++) {
                    int m = m0 + wm * 64 + i * 16 + rbase + r;
                    C[(size_t)m * ldc + n] = acc[i][j][r];
                }
            }
    } else {
        // ---- go: fp32 TN GEMM, M=20, t-major k; B bits straight from gmask --
        float* Asf = (float*)As;
        float* Bsf = (float*)Bs;
        const float* A = ws + O_ERR;
        const unsigned long long* gm = (const unsigned long long*)(ws + O_MSK);
        int v = bx - 160;
        int s = v & 7, nt = v >> 3;
        int n0 = nt * 64, k0 = s * 800;
        int w0 = n0 >> 6;
        int tx = tid & 15, ty = tid >> 4;
        float acc[4][4] = {};
        for (int kb = 0; kb < 800; kb += 16) {
            #pragma unroll
            for (int e = tid; e < 1024; e += 256) {
                int kk = e >> 6, c = e & 63;
                size_t gk = (size_t)(k0 + kb + kk);
                Asf[kk * 64 + c] = (c < kNO) ? A[gk * kNO + c] : 0.f;
                Bsf[kk * 64 + c] = (float)((gm[gk * 8 + w0] >> c) & 1ull);
            }
            __syncthreads();
            #pragma unroll
            for (int kk = 0; kk < 16; kk++) {
                float4 av = *(const float4*)&Asf[kk * 64 + ty * 4];
                float4 bv = *(const float4*)&Bsf[kk * 64 + tx * 4];
                float aa[4] = {av.x, av.y, av.z, av.w};
                float bb[4] = {bv.x, bv.y, bv.z, bv.w};
                #pragma unroll
                for (int a = 0; a < 4; a++)
                    #pragma unroll
                    for (int c = 0; c < 4; c++) acc[a][c] += aa[a] * bb[c];
            }
            __syncthreads();
        }
        float* Cs = ws + O_PGO + (size_t)s * kNO * kNH;
        #pragma unroll
        for (int a = 0; a < 4; a++) {
            int m = ty * 4 + a;
            if (m >= kNO) continue;
            #pragma unroll
            for (int c = 0; c < 4; c++)
                Cs[(size_t)m * kNH + n0 + tx * 4 + c] = acc[a][c];
        }
    }
}

// ---- merged reduction: gf (4 slices), gr (4 slices), go (8 slices) ----------
__global__ void k_reduce_all(const float* __restrict__ ws, float* __restrict__ dout) {
    int idx = blockIdx.x * 256 + threadIdx.x;  // < 630784
    const int NGF = kNH * kNI, NGR = kNH * kNH, NGO = kNO * kNH;
    float s = 0.f;
    if (idx < NGF) {
        int m = idx / kNI, n = idx - m * kNI;
        size_t src = O_PGF + (size_t)m * 768 + n;
        #pragma unroll
        for (int k = 0; k < 4; k++) s += ws[src + (size_t)k * kNH * 768];
        dout[OUT_GF + idx] = s;   // LR folded into mtb
    } else if (idx < NGF + NGR) {
        int j = idx - NGF;
        #pragma unroll
        for (int k = 0; k < 4; k++) s += ws[O_PGR + j + (size_t)k * NGR];
        dout[OUT_GR + j] = s;
    } else if (idx < NGF + NGR + NGO) {
        int j = idx - NGF - NGR;
        #pragma unroll
        for (int k = 0; k < 8; k++) s += ws[O_PGO + (size_t)k * NGO + j];
        dout[OUT_GO + j] = LR * s;
    }
}

extern "C" void kernel_launch(void* const* d_in, const int* in_sizes, int n_in,
                              void* d_out, int out_size, void* d_ws, size_t ws_size,
                              hipStream_t stream) {
    (void)in_sizes; (void)n_in; (void)out_size;
    const float* x     = (const float*)d_in[0];
    const float* label = (const float*)d_in[1];
    const float* w_fc1 = (const float*)d_in[3];
    const float* w_rec = (const float*)d_in[4];
    const float* w_out = (const float*)d_in[5];
    float* out = (float*)d_out;
    float* ws  = (float*)d_ws;

    if (ws_size < WS_FLOATS * sizeof(float)) return;

    unsigned long long* gmask = (unsigned long long*)(ws + O_MSK);

    k_xw2<<<200, 256, 0, stream>>>(x, w_fc1, ws + O_XW);

    k_forward<<<kB + 54, 832, 0, stream>>>(ws, label, w_rec, w_out, out, gmask, x);

    k_grads<<<224, 256, 0, stream>>>(ws);               // gf + gr + go in one launch

    k_reduce_all<<<2464, 256, 0, stream>>>(ws, out);
}

// Round 13
// 608.718 us; speedup vs baseline: 1.6783x; 1.0415x over previous
//
#include <hip/hip_runtime.h>
#include <hip/hip_bf16.h>

// Problem constants (B,T,NI,NH,NO fixed by the reference)
constexpr int kB  = 64;
constexpr int kT  = 100;
constexpr int kNI = 700;
constexpr int kNH = 512;
constexpr int kNO = 20;
constexpr float TAU   = 0.6f;
constexpr float TAU_O = 0.6f;
constexpr float THR   = 0.6f;
constexpr float LR    = 0.05f;

constexpr size_t BNH = (size_t)kB * kNH;   // 32768
constexpr size_t BNI = (size_t)kB * kNI;   // 44800
constexpr size_t BNO = (size_t)kB * kNO;   // 1280
constexpr int kK   = kT * kB;              // 6400 (grad-GEMM K; b-major: k = b*100+t)
constexpr int kKP  = 704;                  // padded K for xw GEMM

typedef __attribute__((ext_vector_type(8))) short short8;
typedef __attribute__((ext_vector_type(4))) float f32x4;

// ---------------- workspace layout (float offsets) ---------------------------
constexpr size_t O_XW   = 0;                                // [T, t*64+b, NH] 3,276,800
constexpr size_t O_PGF  = 0;                                // 4 x [512][768]
constexpr size_t O_PGR  = 1572864;                          // 4 x [512][512]
constexpr size_t O_PGO  = 2621440;                          // 8 x [20][512]
constexpr size_t O_HSUR = 3276800;                          // [T,B,NH]
constexpr size_t O_ERR  = 6553600;                          // [T,B,NO] errf
constexpr size_t O_MTB  = 6681600;                          // bf16 [512][6400], b-major k
constexpr size_t O_TRB  = 8320000;                          // bf16 [512][6400], b-major k
constexpr size_t O_MSK  = 9958400;                          // u64 [T][B][8]
constexpr size_t O_TIB  = 10060800;                         // bf16 [700][6400]
constexpr size_t O_CNT  = 12300800;                         // 48 int tile counters
constexpr size_t WS_FLOATS = 12300864;                      // ~49.2 MB

// d_out layout
constexpr size_t OUT_GF = (size_t)kB * kT * kNO;
constexpr size_t OUT_GR = OUT_GF + (size_t)kNH * kNI;
constexpr size_t OUT_GO = OUT_GR + (size_t)kNH * kNH;

// ---- XW = Xperm @ w_fc1^T : C[m=t*64+b, n<512], K=704 (fp32, exact) ---------
// 128x64 tiles (400 blocks) -> ~2 waves/SIMD latency hiding vs 1 at 128x128.
// Per-element K accumulation order identical to before -> XW bit-identical.
__global__ __launch_bounds__(256) void k_xw2(const float* __restrict__ x,
                                             const float* __restrict__ wfc,
                                             float* __restrict__ XW) {
    int bx = blockIdx.x;                 // 400 = 50 mt x 8 nt
    int mt = bx % 50, nt = bx / 50;
    int m0 = mt * 128, n0 = nt * 64;
    int tid = threadIdx.x, tx = tid & 15, ty = tid >> 4;
    __shared__ float As[128][20];
    __shared__ float Bs[16][64];
    float acc[8][4] = {};
    int arow = tid >> 1, ahalf = tid & 1;
    int bb = (m0 + arow) & 63, tt = (m0 + arow) >> 6;
    const float* ap = x + ((size_t)bb * kT + tt) * kNI;
    int br = tid >> 2, bc4 = tid & 3;    // B stage: row n0+br, k-chunk bc4
    const float* wp = wfc + (size_t)(n0 + br) * kNI;
    for (int k0 = 0; k0 < kKP; k0 += 16) {
        #pragma unroll
        for (int u = 0; u < 2; u++) {
            int k = k0 + ahalf * 8 + u * 4;
            float4 v = (k + 3 < kNI) ? *(const float4*)(ap + k)
                                     : make_float4(0.f, 0.f, 0.f, 0.f);
            *(float4*)&As[arow][ahalf * 8 + u * 4] = v;
        }
        {
            int k = k0 + bc4 * 4;
            float4 v = (k + 3 < kNI) ? *(const float4*)(wp + k)
                                     : make_float4(0.f, 0.f, 0.f, 0.f);
            Bs[bc4 * 4 + 0][br] = v.x; Bs[bc4 * 4 + 1][br] = v.y;
            Bs[bc4 * 4 + 2][br] = v.z; Bs[bc4 * 4 + 3][br] = v.w;
        }
        __syncthreads();
        #pragma unroll
        for (int kk = 0; kk < 16; kk++) {
            float av[8];
            #pragma unroll
            for (int i = 0; i < 4; i++) {
                av[i]     = As[ty * 4 + i][kk];
                av[4 + i] = As[64 + ty * 4 + i][kk];
            }
            float4 b0 = *(const float4*)&Bs[kk][tx * 4];
            float bv[4] = {b0.x, b0.y, b0.z, b0.w};
            #pragma unroll
            for (int i = 0; i < 8; i++)
                #pragma unroll
                for (int j = 0; j < 4; j++) acc[i][j] += av[i] * bv[j];
        }
        __syncthreads();
    }
    #pragma unroll
    for (int i = 0; i < 8; i++) {
        int m = m0 + ((i < 4) ? (ty * 4 + i) : (64 + ty * 4 + i - 4));
        float* dst = XW + (size_t)m * kNH + n0;
        *(float4*)(dst + tx * 4) = make_float4(acc[i][0], acc[i][1], acc[i][2], acc[i][3]);
    }
}

// ---- fused forward + hidden tib cast ----------------------------------------
__global__ __launch_bounds__(832) void k_forward(float* __restrict__ ws,
                                                 const float* __restrict__ label,
                                                 const float* __restrict__ w_rec,
                                                 const float* __restrict__ w_out,
                                                 float* __restrict__ dout,
                                                 unsigned long long* __restrict__ gmask,
                                                 const float* __restrict__ x) {
    __shared__ float wout_ld[kNO * kNH];          // 40 KB
    __shared__ float partial[8][kNH];             // 16 KB
    __shared__ unsigned long long mh[kT * 8];     // 6.4 KB mask history
    __shared__ float errh[kT * kNO];              // 8 KB err/errf history

    int bxg = blockIdx.x, tid = threadIdx.x;
    if (bxg >= kB) {
        // tib[n=i][b*100+t] = bf16(tin scan of x), hidden under the forward
        int idx = (bxg - kB) * 832 + tid;
        if (idx < (int)BNI) {
            int b = idx / kNI, i = idx - b * kNI;
            const float* xp = x + (size_t)b * kT * kNI + i;
            unsigned short* tib = (unsigned short*)(ws + O_TIB);
            size_t rowoff = (size_t)i * kK + (size_t)b * 100;
            float v = 0.f;
            for (int tq = 0; tq < 25; tq++) {
                unsigned long long w8 = 0;
                #pragma unroll
                for (int u = 0; u < 4; u++) {
                    int t = tq * 4 + u;
                    v = TAU * v + xp[(size_t)t * kNI];
                    __hip_bfloat16 bv = __float2bfloat16(v);
                    w8 |= ((unsigned long long)*(unsigned short*)&bv) << (16 * u);
                }
                *(unsigned long long*)&tib[rowoff + tq * 4] = w8;
            }
        }
        return;
    }

    int b = bxg;
    int wave = tid >> 6, lane = tid & 63;
    const f32x4* wr4 = (const f32x4*)w_rec;
    for (int e = tid; e < kNO * kNH; e += 832) wout_ld[e] = w_out[e];
    float hm = 0.f, sp_prev = 0.f;
    float om_r[4] = {0.f, 0.f, 0.f, 0.f}, os_r[4] = {0.f, 0.f, 0.f, 0.f};
    int q = wave - 8;
    const int coff = lane * 2;
    __syncthreads();

    for (int t = 0; t < kT; t++) {
        float xw = 0.f;
        if (wave < 8) {
            xw = ws[O_XW + ((size_t)t * 64 + b) * kNH + tid];
            unsigned long long m = (t > 0) ? mh[(t - 1) * 8 + wave] : 0ull;
            const size_t base = (size_t)wave * 64;
            f32x4 s0 = {0.f, 0.f, 0.f, 0.f}, s1 = s0;
            while (m) {
                int j = __builtin_ctzll(m); m &= m - 1;
                const f32x4* r = wr4 + (base + j) * 128 + coff;
                s0 += r[0]; s1 += r[1];
            }
            *(f32x4*)&partial[wave][lane * 8]     = s0;
            *(f32x4*)&partial[wave][lane * 8 + 4] = s1;
        } else if (t > 0) {
            int to = t - 1;
            unsigned long long mk[8];
            #pragma unroll
            for (int k = 0; k < 8; k++) mk[k] = mh[to * 8 + k];
            #pragma unroll
            for (int r = 0; r < 4; r++) {
                int o = q * 4 + r;
                float p = 0.f;
                #pragma unroll
                for (int k = 0; k < 8; k++)
                    if ((mk[k] >> lane) & 1) p += wout_ld[o * kNH + 64 * k + lane];
                #pragma unroll
                for (int off = 32; off >= 1; off >>= 1) p += __shfl_xor(p, off);
                if (lane == 0) {
                    float om_n = TAU * om_r[r] * (1.f - os_r[r]) + p;
                    float os_n = (om_n >= THR) ? 1.f : 0.f;
                    om_r[r] = om_n; os_r[r] = os_n;
                    errh[to * kNO + o] = os_n - label[((size_t)b * kT + to) * kNO + o];
                    dout[((size_t)b * kT + to) * kNO + o] = os_n;
                }
            }
        }
        __syncthreads();
        if (tid < kNH) {
            float rec = ((partial[0][tid] + partial[1][tid]) + (partial[2][tid] + partial[3][tid]))
                      + ((partial[4][tid] + partial[5][tid]) + (partial[6][tid] + partial[7][tid]));
            hm = TAU * hm * (1.f - sp_prev) + (xw + rec);
            bool v = (hm >= THR);
            float sp = v ? 1.f : 0.f;
            sp_prev = sp;
            ws[O_HSUR + (size_t)t * BNH + (size_t)b * kNH + tid] =
                TAU * fmaxf(0.f, 1.f - fabsf(hm - THR) * (1.f / THR));
            unsigned long long bal = __ballot(v);
            if (lane == 0) {
                mh[t * 8 + wave] = bal;
                gmask[((size_t)t * 64 + b) * 8 + wave] = bal;
            }
        }
        __syncthreads();
    }
    // tail 1a: output layer for t = 99
    if (wave >= 8) {
        int to = kT - 1;
        unsigned long long mk[8];
        #pragma unroll
        for (int k = 0; k < 8; k++) mk[k] = mh[to * 8 + k];
        #pragma unroll
        for (int r = 0; r < 4; r++) {
            int o = q * 4 + r;
            float p = 0.f;
            #pragma unroll
            for (int k = 0; k < 8; k++)
                if ((mk[k] >> lane) & 1) p += wout_ld[o * kNH + 64 * k + lane];
            #pragma unroll
            for (int off = 32; off >= 1; off >>= 1) p += __shfl_xor(p, off);
            if (lane == 0) {
                float om_n = TAU * om_r[r] * (1.f - os_r[r]) + p;
                float os_n = (om_n >= THR) ? 1.f : 0.f;
                errh[to * kNO + o] = os_n - label[((size_t)b * kT + to) * kNO + o];
                dout[((size_t)b * kT + to) * kNO + o] = os_n;
            }
        }
    }
    // tail 1b (concurrent): trb[n][b*100+t] = bf16(trec) from mh
    if (tid < kNH) {
        unsigned short* trb = (unsigned short*)(ws + O_TRB);
        size_t rowoff = (size_t)tid * kK + (size_t)b * 100;
        int w = tid >> 6, bit = tid & 63;
        float v = 0.f, p = 0.f;
        for (int tq = 0; tq < 25; tq++) {
            unsigned long long w8 = 0;
            #pragma unroll
            for (int u = 0; u < 4; u++) {
                int t = tq * 4 + u;
                v = TAU * v + p;
                __hip_bfloat16 bv = __float2bfloat16(v);
                w8 |= ((unsigned long long)*(unsigned short*)&bv) << (16 * u);
                p = (float)((mh[t * 8 + w] >> bit) & 1ull);
            }
            *(unsigned long long*)&trb[rowoff + tq * 4] = w8;
        }
    }
    __syncthreads();
    // tail 2: reverse kappa scan (LDS) + errf -> global (t-major, for go)
    if (wave == 8 && lane < kNO) {
        float v = 0.f;
        for (int t = kT - 1; t >= 0; t--) {
            v = errh[t * kNO + lane] + TAU_O * v;
            errh[t * kNO + lane] = v;
            ws[O_ERR + (size_t)t * BNO + (size_t)b * kNO + lane] = v;
        }
    }
    __syncthreads();
    // tail 3: mtb[r][b*100+t] = bf16(LR*(errf@w_out)[r]*hsur[t][b][r])
    if (tid < kNH) {
        float wreg[kNO];
        #pragma unroll
        for (int o = 0; o < kNO; o++) wreg[o] = wout_ld[o * kNH + tid];
        unsigned short* mtb = (unsigned short*)(ws + O_MTB);
        size_t rowoff = (size_t)tid * kK + (size_t)b * 100;
        for (int tq = 0; tq < 25; tq++) {
            unsigned long long w8 = 0;
            #pragma unroll
            for (int u = 0; u < 4; u++) {
                int t = tq * 4 + u;
                float s = 0.f;
                #pragma unroll
                for (int o = 0; o < kNO; o++) s += errh[t * kNO + o] * wreg[o];
                float val = LR * s * ws[O_HSUR + (size_t)t * BNH + (size_t)b * kNH + tid];
                __hip_bfloat16 bv = __float2bfloat16(val);
                w8 |= ((unsigned long long)*(unsigned short*)&bv) << (16 * u);
            }
            *(unsigned long long*)&mtb[rowoff + tq * 4] = w8;
        }
    }
}

// ---- merged grads + self-reduction ------------------------------------------
// Blocks 0..95 gf (MFMA), 96..159 gr (MFMA), 160..223 go (fp32). Each split-K
// tile group has a counter; the LAST sibling (agent-scope ACQ_REL fetch_add)
// reduces the slices into dout — same ascending-slice order as the old
// k_reduce_all (bit-identical), no extra launch, no co-residency assumption.
__global__ __launch_bounds__(256) void k_grads(float* __restrict__ ws,
                                               float* __restrict__ dout) {
    __shared__ unsigned short As[128 * 72];
    __shared__ unsigned short Bs[128 * 72];
    __shared__ int isLast;
    int bx = blockIdx.x, tid = threadIdx.x;
    int* cnt = (int*)(ws + O_CNT);

    if (bx < 160) {
        constexpr int KC = kK / 4, BK = 64, LDT = 72;
        const unsigned short* A = (const unsigned short*)(ws + O_MTB);
        const unsigned short* B;
        float* Cpart;
        int Nrows, ldc, s, mt, nt, tileid;
        if (bx < 96) {
            s = bx & 3; mt = (bx >> 2) & 3; nt = bx >> 4;
            B = (const unsigned short*)(ws + O_TIB);
            Cpart = ws + O_PGF; Nrows = kNI; ldc = 768;
            tileid = mt + 4 * nt;                       // 0..23
        } else {
            int v = bx - 96;
            s = v & 3; mt = (v >> 2) & 3; nt = v >> 4;
            B = (const unsigned short*)(ws + O_TRB);
            Cpart = ws + O_PGR; Nrows = kNH; ldc = kNH;
            tileid = 24 + mt + 4 * nt;                  // 24..39
        }
        int m0 = mt * 128, n0 = nt * 128, k0 = s * KC;
        int wave = tid >> 6, lane = tid & 63;
        int wm = wave & 1, wn = wave >> 1;
        f32x4 acc[4][4];
        #pragma unroll
        for (int i = 0; i < 4; i++)
            #pragma unroll
            for (int j = 0; j < 4; j++) acc[i][j] = (f32x4){0.f, 0.f, 0.f, 0.f};

        for (int kb = 0; kb < KC; kb += BK) {
            int kg = k0 + kb;
            #pragma unroll
            for (int p = 0; p < 4; p++) {
                int f = tid + p * 256;
                int row = f >> 3, seg = f & 7;
                *(short8*)&As[row * LDT + seg * 8] =
                    *(const short8*)&A[(size_t)(m0 + row) * kK + kg + seg * 8];
                short8 bv = {};
                if (n0 + row < Nrows)
                    bv = *(const short8*)&B[(size_t)(n0 + row) * kK + kg + seg * 8];
                *(short8*)&Bs[row * LDT + seg * 8] = bv;
            }
            __syncthreads();
            #pragma unroll
            for (int h = 0; h < 2; h++) {
                int kof = h * 32 + (lane >> 4) * 8;
                short8 af[4], bf[4];
                #pragma unroll
                for (int i = 0; i < 4; i++)
                    af[i] = *(short8*)&As[(wm * 64 + i * 16 + (lane & 15)) * LDT + kof];
                #pragma unroll
                for (int j = 0; j < 4; j++)
                    bf[j] = *(short8*)&Bs[(wn * 64 + j * 16 + (lane & 15)) * LDT + kof];
                #pragma unroll
                for (int i = 0; i < 4; i++)
                    #pragma unroll
                    for (int j = 0; j < 4; j++)
                        acc[i][j] = __builtin_amdgcn_mfma_f32_16x16x32_bf16(af[i], bf[j], acc[i][j], 0, 0, 0);
            }
            __syncthreads();
        }
        float* C = Cpart + (size_t)s * kNH * ldc;
        int rbase = (lane >> 4) * 4, col = lane & 15;
        #pragma unroll
        for (int i = 0; i < 4; i++)
            #pragma unroll
            for (int j = 0; j < 4; j++) {
                int n = n0 + wn * 64 + j * 16 + col;
                #pragma unroll
                for (int r = 0; r < 4; r++) {
                    int m = m0 + wm * 64 + i * 16 + rbase + r;
                    C[(size_t)m * ldc + n] = acc[i][j][r];
                }
            }
        // ---- last-sibling reduction ----
        __syncthreads();   // drain partial stores (vmcnt) before release
        if (tid == 0)
            isLast = (__hip_atomic_fetch_add(&cnt[tileid], 1, __ATOMIC_ACQ_REL,
                                             __HIP_MEMORY_SCOPE_AGENT) == 3);
        __syncthreads();
        if (isLast) {
            if (bx < 96) {
                for (int e = tid; e < 128 * 128; e += 256) {
                    int m = m0 + (e >> 7), n = n0 + (e & 127);
                    if (n < kNI) {
                        float sv = 0.f;
                        size_t src = O_PGF + (size_t)m * 768 + n;
                        #pragma unroll
                        for (int k = 0; k < 4; k++) sv += ws[src + (size_t)k * kNH * 768];
                        dout[OUT_GF + (size_t)m * kNI + n] = sv;   // LR folded into mtb
                    }
                }
            } else {
                for (int e = tid; e < 128 * 128; e += 256) {
                    int m = m0 + (e >> 7), n = n0 + (e & 127);
                    float sv = 0.f;
                    size_t src = O_PGR + (size_t)m * kNH + n;
                    #pragma unroll
                    for (int k = 0; k < 4; k++) sv += ws[src + (size_t)k * kNH * kNH];
                    dout[OUT_GR + (size_t)m * kNH + n] = sv;
                }
            }
        }
    } else {
        // ---- go: fp32 TN GEMM, M=20, t-major k; B bits from gmask ----
        float* Asf = (float*)As;
        float* Bsf = (float*)Bs;
        const float* A = ws + O_ERR;
        const unsigned long long* gm = (const unsigned long long*)(ws + O_MSK);
        int v = bx - 160;
        int s = v & 7, nt = v >> 3;
        int n0 = nt * 64, k0 = s * 800;
        int w0 = n0 >> 6;
        int tx = tid & 15, ty = tid >> 4;
        float acc[4][4] = {};
        for (int kb = 0; kb < 800; kb += 16) {
            #pragma unroll
            for (int e = tid; e < 1024; e += 256) {
                int kk = e >> 6, c = e & 63;
                size_t gk = (size_t)(k0 + kb + kk);
                Asf[kk * 64 + c] = (c < kNO) ? A[gk * kNO + c] : 0.f;
                Bsf[kk * 64 + c] = (float)((gm[gk * 8 + w0] >> c) & 1ull);
            }
            __syncthreads();
            #pragma unroll
            for (int kk = 0; kk < 16; kk++) {
                float4 av = *(const float4*)&Asf[kk * 64 + ty * 4];
                float4 bv = *(const float4*)&Bsf[kk * 64 + tx * 4];
                float aa[4] = {av.x, av.y, av.z, av.w};
                float bb[4] = {bv.x, bv.y, bv.z, bv.w};
                #pragma unroll
                for (int a = 0; a < 4; a++)
                    #pragma unroll
                    for (int c = 0; c < 4; c++) acc[a][c] += aa[a] * bb[c];
            }
            __syncthreads();
        }
        float* Cs = ws + O_PGO + (size_t)s * kNO * kNH;
        #pragma unroll
        for (int a = 0; a < 4; a++) {
            int m = ty * 4 + a;
            if (m < kNO) {
                #pragma unroll
                for (int c = 0; c < 4; c++)
                    Cs[(size_t)m * kNH + n0 + tx * 4 + c] = acc[a][c];
            }
        }
        // ---- last-sibling reduction (8 slices) ----
        __syncthreads();
        if (tid == 0)
            isLast = (__hip_atomic_fetch_add(&cnt[40 + nt], 1, __ATOMIC_ACQ_REL,
                                             __HIP_MEMORY_SCOPE_AGENT) == 7);
        __syncthreads();
        if (isLast) {
            for (int e = tid; e < kNO * 64; e += 256) {
                int o = e >> 6, c = e & 63;
                float sv = 0.f;
                size_t src = O_PGO + (size_t)o * kNH + n0 + c;
                #pragma unroll
                for (int k = 0; k < 8; k++) sv += ws[src + (size_t)k * kNO * kNH];
                dout[OUT_GO + (size_t)o * kNH + n0 + c] = LR * sv;
            }
        }
    }
}

extern "C" void kernel_launch(void* const* d_in, const int* in_sizes, int n_in,
                              void* d_out, int out_size, void* d_ws, size_t ws_size,
                              hipStream_t stream) {
    (void)in_sizes; (void)n_in; (void)out_size;
    const float* x     = (const float*)d_in[0];
    const float* label = (const float*)d_in[1];
    const float* w_fc1 = (const float*)d_in[3];
    const float* w_rec = (const float*)d_in[4];
    const float* w_out = (const float*)d_in[5];
    float* out = (float*)d_out;
    float* ws  = (float*)d_ws;

    if (ws_size < WS_FLOATS * sizeof(float)) return;

    unsigned long long* gmask = (unsigned long long*)(ws + O_MSK);

    hipMemsetAsync(ws + O_CNT, 0, 64 * sizeof(int), stream);   // tile counters

    k_xw2<<<400, 256, 0, stream>>>(x, w_fc1, ws + O_XW);

    k_forward<<<kB + 54, 832, 0, stream>>>(ws, label, w_rec, w_out, out, gmask, x);

    k_grads<<<224, 256, 0, stream>>>(ws, out);   // gf + gr + go + reductions

}